// Round 9
// baseline (284.715 us; speedup 1.0000x reference)
//
#include <hip/hip_runtime.h>
#include <math.h>

#define TT   2048
#define BB   8
#define DIM_ 1024
#define DI_  2048
#define NS_  64
#define MR_  (TT * BB)   // 16384 rows (t-major, b-minor)
#define NCH  32          // chunks of 64 steps
#define LD   68          // padded LDS leading dim (16B-aligned rows)
#define KSPL 16          // split-K factor for fuse GEMM
#define KCH  (DI_ / KSPL)
#define NGRP 8           // scan groups
#define GSZ  4           // chunks per group (NGRP*GSZ == NCH)
#define LDH2 40          // padded f16 LDS stride for gemm_h16 (80 B rows)

typedef _Float16 half8 __attribute__((ext_vector_type(8)));
typedef _Float16 half4h __attribute__((ext_vector_type(4)));
typedef float floatx4 __attribute__((ext_vector_type(4)));

__device__ __forceinline__ float dot4(float4 a, float4 b) {
  return a.x * b.x + a.y * b.y + a.z * b.z + a.w * b.w;
}

__device__ __forceinline__ half8 cvt8(float4 lo, float4 hi) {
  half8 h = {(_Float16)lo.x, (_Float16)lo.y, (_Float16)lo.z, (_Float16)lo.w,
             (_Float16)hi.x, (_Float16)hi.y, (_Float16)hi.z, (_Float16)hi.w};
  return h;
}

// ---------------------------------------------------------------------------
// fp32 -> f16 elementwise convert (n8 groups of 8 elems), grid-stride.
// ---------------------------------------------------------------------------
__global__ __launch_bounds__(256) void cvt_f16_kernel(
    const float* __restrict__ in, _Float16* __restrict__ out, long n8) {
  long i = (long)blockIdx.x * 256 + threadIdx.x;
  const long stride = (long)gridDim.x * 256;
  for (; i < n8; i += stride) {
    const float4 lo = *(const float4*)&in[i * 8];
    const float4 hi = *(const float4*)&in[i * 8 + 4];
    *(half8*)&out[i * 8] = cvt8(lo, hi);
  }
}

// ---------------------------------------------------------------------------
// f16 MFMA GEMM: C[M,N] = A[M,K] * B[N,K]^T, A/B already f16 row-major.
// BM=64 x BN=64 tile, BK=32, 4 waves in 2x2 (wave tile 32x32, 2x2 MFMA).
// ---------------------------------------------------------------------------
__global__ __launch_bounds__(256) void gemm_h16(
    const _Float16* __restrict__ A, const _Float16* __restrict__ B,
    float* __restrict__ C, int M, int N, int K) {
  __shared__ __align__(16) _Float16 Ah[2][64 * LDH2];  // 2 x 5 KB
  __shared__ __align__(16) _Float16 Bh[2][64 * LDH2];  // 2 x 5 KB
  const int tid  = threadIdx.x;
  const int m0   = blockIdx.y * 64;
  const int n0   = blockIdx.x * 64;
  const int wave = tid >> 6, lane = tid & 63;
  const int wm   = (wave >> 1) * 32;   // wave row base (0/32)
  const int wn   = (wave & 1) * 32;    // wave col base (0/32)
  const int quad = lane >> 4, l16 = lane & 15;
  const int srow = tid >> 2;           // stage row 0..63
  const int scol = (tid & 3) * 8;      // stage k-offset (f16 elems)

  const _Float16* Ap = A + (size_t)(m0 + srow) * K + scol;
  const _Float16* Bp = B + (size_t)(n0 + srow) * K + scol;

  floatx4 acc[2][2];
#pragma unroll
  for (int i = 0; i < 2; ++i)
#pragma unroll
    for (int j = 0; j < 2; ++j) acc[i][j] = (floatx4)0.f;

  half8 ha, hb;
  // prologue: load + stage tile 0
  ha = *(const half8*)(Ap);
  hb = *(const half8*)(Bp);
  *(half8*)&Ah[0][srow * LDH2 + scol] = ha;
  *(half8*)&Bh[0][srow * LDH2 + scol] = hb;
  __syncthreads();

  const int NK = K >> 5;
  for (int kt = 0; kt < NK; ++kt) {
    const int cur = kt & 1;
    if (kt + 1 < NK) {
      ha = *(const half8*)(Ap + (kt + 1) * 32);
      hb = *(const half8*)(Bp + (kt + 1) * 32);
    }
    half8 af[2], bf[2];
#pragma unroll
    for (int mt = 0; mt < 2; ++mt)
      af[mt] = *(const half8*)&Ah[cur][(wm + mt * 16 + l16) * LDH2 + quad * 8];
#pragma unroll
    for (int nt = 0; nt < 2; ++nt)
      bf[nt] = *(const half8*)&Bh[cur][(wn + nt * 16 + l16) * LDH2 + quad * 8];
#pragma unroll
    for (int mt = 0; mt < 2; ++mt)
#pragma unroll
      for (int nt = 0; nt < 2; ++nt)
        acc[mt][nt] = __builtin_amdgcn_mfma_f32_16x16x32_f16(
            af[mt], bf[nt], acc[mt][nt], 0, 0, 0);
    if (kt + 1 < NK) {
      const int nxt = cur ^ 1;
      *(half8*)&Ah[nxt][srow * LDH2 + scol] = ha;
      *(half8*)&Bh[nxt][srow * LDH2 + scol] = hb;
    }
    __syncthreads();
  }

#pragma unroll
  for (int mt = 0; mt < 2; ++mt) {
#pragma unroll
    for (int i = 0; i < 4; ++i) {
      const size_t r = (size_t)(m0 + wm + mt * 16 + quad * 4 + i) * N;
#pragma unroll
      for (int nt = 0; nt < 2; ++nt)
        C[r + n0 + wn + nt * 16 + l16] = acc[mt][nt][i];
    }
  }
}

// ---------------------------------------------------------------------------
// fuse GEMM (split-K): Pg[ks] partial of Wf[256][1024] = Wg[256][2048]*Win[2048][1024]
// ---------------------------------------------------------------------------
__global__ __launch_bounds__(256) void fuse_gemm_kernel(
    const float* __restrict__ Wk, const float* __restrict__ Wv,
    const float* __restrict__ Wq, const float* __restrict__ Wz,
    const float* __restrict__ Win, float* __restrict__ Pg) {
  __shared__ __align__(16) float As[16][132];
  __shared__ __align__(16) float Bs[16][132];
  const int tid = threadIdx.x;
  const int n0  = blockIdx.x * 128;
  const int m0  = blockIdx.y * 128;
  const int kb  = blockIdx.z * KCH;
  const int lrow = tid >> 2;
  const int lk4  = (tid & 3) << 2;
  const int tm   = (tid & 15) << 2;
  const int tn   = (tid >> 4) << 2;
  const float* Wg[4] = {Wk, Wv, Wq, Wz};
  const int ra = m0 + lrow, rb = m0 + 64 + lrow;
  const float* arow0 = Wg[ra >> 6] + (size_t)(ra & 63) * DI_;
  const float* arow1 = Wg[rb >> 6] + (size_t)(rb & 63) * DI_;
  const int brow = tid >> 5;
  const int bcol = (tid & 31) << 2;

  float acc[8][8];
#pragma unroll
  for (int i = 0; i < 8; ++i)
#pragma unroll
    for (int j = 0; j < 8; ++j) acc[i][j] = 0.f;

  for (int k0 = 0; k0 < KCH; k0 += 16) {
    float4 av0 = *(const float4*)&arow0[kb + k0 + lk4];
    float4 av1 = *(const float4*)&arow1[kb + k0 + lk4];
    float4 bv0 = *(const float4*)&Win[(size_t)(kb + k0 + brow)     * DIM_ + n0 + bcol];
    float4 bv1 = *(const float4*)&Win[(size_t)(kb + k0 + 8 + brow) * DIM_ + n0 + bcol];
    __syncthreads();
    As[lk4 + 0][lrow] = av0.x; As[lk4 + 1][lrow] = av0.y;
    As[lk4 + 2][lrow] = av0.z; As[lk4 + 3][lrow] = av0.w;
    As[lk4 + 0][64 + lrow] = av1.x; As[lk4 + 1][64 + lrow] = av1.y;
    As[lk4 + 2][64 + lrow] = av1.z; As[lk4 + 3][64 + lrow] = av1.w;
    *(float4*)&Bs[brow][bcol]     = bv0;
    *(float4*)&Bs[brow + 8][bcol] = bv1;
    __syncthreads();
#pragma unroll
    for (int kk = 0; kk < 16; ++kk) {
      float4 a0 = *(const float4*)&As[kk][tm];
      float4 a1 = *(const float4*)&As[kk][tm + 64];
      float4 b0 = *(const float4*)&Bs[kk][tn];
      float4 b1 = *(const float4*)&Bs[kk][tn + 64];
      float ar[8] = {a0.x, a0.y, a0.z, a0.w, a1.x, a1.y, a1.z, a1.w};
      float br[8] = {b0.x, b0.y, b0.z, b0.w, b1.x, b1.y, b1.z, b1.w};
#pragma unroll
      for (int i = 0; i < 8; ++i)
#pragma unroll
        for (int j = 0; j < 8; ++j)
          acc[i][j] = fmaf(ar[i], br[j], acc[i][j]);
    }
  }
  float* P = Pg + (size_t)blockIdx.z * (256 * DIM_);
#pragma unroll
  for (int i = 0; i < 8; ++i) {
    int r = m0 + tm + (i & 3) + ((i >> 2) << 6);
    float4 c0 = make_float4(acc[i][0], acc[i][1], acc[i][2], acc[i][3]);
    float4 c1 = make_float4(acc[i][4], acc[i][5], acc[i][6], acc[i][7]);
    *(float4*)&P[(size_t)r * DIM_ + n0 + tn]      = c0;
    *(float4*)&P[(size_t)r * DIM_ + n0 + tn + 64] = c1;
  }
}

// Wf_h[i] = (f16) sum_ks Pg[ks][i]
__global__ __launch_bounds__(256) void fuse_reduce_kernel(
    const float* __restrict__ Pg, _Float16* __restrict__ Wfh) {
  const size_t i = ((size_t)blockIdx.x * 256 + threadIdx.x) << 2;
  float4 s = *(const float4*)&Pg[i];
#pragma unroll
  for (int ks = 1; ks < KSPL; ++ks) {
    float4 p = *(const float4*)&Pg[(size_t)ks * (256 * DIM_) + i];
    s.x += p.x; s.y += p.y; s.z += p.z; s.w += p.w;
  }
  half4h h = {(_Float16)s.x, (_Float16)s.y, (_Float16)s.z, (_Float16)s.w};
  *(half4h*)&Wfh[i] = h;
}

// ---------------------------------------------------------------------------
// Unit-normalize each k row (first 64 cols of kvqz).
// ---------------------------------------------------------------------------
__global__ __launch_bounds__(256) void norm_k_kernel(float* __restrict__ kvqz) {
  const int wid  = (blockIdx.x * 256 + threadIdx.x) >> 6;
  const int lane = threadIdx.x & 63;
  float x = kvqz[(size_t)wid * 256 + lane];
  float s = x * x;
  s += __shfl_xor(s, 1);  s += __shfl_xor(s, 2);  s += __shfl_xor(s, 4);
  s += __shfl_xor(s, 8);  s += __shfl_xor(s, 16); s += __shfl_xor(s, 32);
  kvqz[(size_t)wid * 256 + lane] = x / (sqrtf(s) + 1e-6f);
}

// ---------------------------------------------------------------------------
// Phase 1: per chunk-batch:  A = K K^T ; Tt = inv(I+stril(A)) (transposed);
// P = T K ; Pv = T V ; M = I - P^T K ; B = Pv^T K.  Store Tt, M, B.
// v3: 4 LDS arrays (Pv written into Vs after its last read; barrier-guarded)
// -> 69.6 KB -> 2 blocks/CU so a co-resident block hides the serial trisolve.
// ---------------------------------------------------------------------------
__global__ __launch_bounds__(256) void phase1_kernel(
    const float* __restrict__ kvqz, float* __restrict__ Tg,
    float* __restrict__ Mg, float* __restrict__ Bg) {
  __shared__ __align__(16) float Ks[64][LD];
  __shared__ __align__(16) float Vs[64][LD];   // V, then Pv
  __shared__ __align__(16) float As[64][LD];   // A=KK^T, then P
  __shared__ __align__(16) float Tt[64][LD];
  const int cb = blockIdx.x;
  const int c  = cb >> 3, b = cb & 7;
  const int t  = threadIdx.x;

  {
    const int tau = t >> 2, m0 = (t & 3) << 4;
    const float* src = kvqz + (size_t)((c * 64 + tau) * BB + b) * 256;
#pragma unroll
    for (int u = 0; u < 4; ++u) {
      *(float4*)&Ks[tau][m0 + 4 * u] = *(const float4*)&src[m0 + 4 * u];
      *(float4*)&Vs[tau][m0 + 4 * u] = *(const float4*)&src[64 + m0 + 4 * u];
    }
  }
  __syncthreads();

  const int i0 = (t >> 4) << 2;
  const int j0 = (t & 15) << 2;

  {  // A = K K^T
    float acc[4][4];
#pragma unroll
    for (int i = 0; i < 4; ++i)
#pragma unroll
      for (int j = 0; j < 4; ++j) acc[i][j] = 0.f;
#pragma unroll 2
    for (int m4 = 0; m4 < 64; m4 += 4) {
      float4 ar[4], br[4];
#pragma unroll
      for (int i = 0; i < 4; ++i) ar[i] = *(const float4*)&Ks[i0 + i][m4];
#pragma unroll
      for (int j = 0; j < 4; ++j) br[j] = *(const float4*)&Ks[j0 + j][m4];
#pragma unroll
      for (int i = 0; i < 4; ++i)
#pragma unroll
        for (int j = 0; j < 4; ++j) acc[i][j] += dot4(ar[i], br[j]);
    }
#pragma unroll
    for (int i = 0; i < 4; ++i)
      *(float4*)&As[i0 + i][j0] =
          make_float4(acc[i][0], acc[i][1], acc[i][2], acc[i][3]);
  }
  __syncthreads();

  if (t < 64) {  // register forward substitution (fully unrolled, tt in VGPRs)
    const int j = t;
    float tt[64];
    tt[0] = (j == 0) ? 1.f : 0.f;
#pragma unroll
    for (int i = 1; i < 64; ++i) {
      float p0 = 0.f, p1 = 0.f, p2 = 0.f, p3 = 0.f;
      const int nf = i >> 2;
#pragma unroll
      for (int s4 = 0; s4 < nf; ++s4) {
        float4 av = *(const float4*)&As[i][4 * s4];   // broadcast (uniform)
        p0 = fmaf(av.x, tt[4 * s4 + 0], p0);
        p1 = fmaf(av.y, tt[4 * s4 + 1], p1);
        p2 = fmaf(av.z, tt[4 * s4 + 2], p2);
        p3 = fmaf(av.w, tt[4 * s4 + 3], p3);
      }
#pragma unroll
      for (int s = 4 * nf; s < i; ++s) p0 = fmaf(As[i][s], tt[s], p0);
      tt[i] = (i == j) ? 1.f : -((p0 + p1) + (p2 + p3));
    }
#pragma unroll
    for (int u = 0; u < 16; ++u)
      *(float4*)&Tt[j][4 * u] = make_float4(tt[4 * u + 0], tt[4 * u + 1],
                                            tt[4 * u + 2], tt[4 * u + 3]);
  }
  __syncthreads();

  {  // P = T K -> As ; Pv = T V -> Vs (barrier before overwrite)
    float accP[4][4], accV[4][4];
#pragma unroll
    for (int i = 0; i < 4; ++i)
#pragma unroll
      for (int j = 0; j < 4; ++j) { accP[i][j] = 0.f; accV[i][j] = 0.f; }
#pragma unroll 4
    for (int s = 0; s < 64; ++s) {
      float4 tv = *(const float4*)&Tt[s][i0];
      float4 kv = *(const float4*)&Ks[s][j0];
      float4 vv = *(const float4*)&Vs[s][j0];
      float ta[4] = {tv.x, tv.y, tv.z, tv.w};
      float ka[4] = {kv.x, kv.y, kv.z, kv.w};
      float va[4] = {vv.x, vv.y, vv.z, vv.w};
#pragma unroll
      for (int i = 0; i < 4; ++i)
#pragma unroll
        for (int j = 0; j < 4; ++j) {
          accP[i][j] = fmaf(ta[i], ka[j], accP[i][j]);
          accV[i][j] = fmaf(ta[i], va[j], accV[i][j]);
        }
    }
    __syncthreads();
#pragma unroll
    for (int i = 0; i < 4; ++i) {
      *(float4*)&As[i0 + i][j0] =
          make_float4(accP[i][0], accP[i][1], accP[i][2], accP[i][3]);
      *(float4*)&Vs[i0 + i][j0] =
          make_float4(accV[i][0], accV[i][1], accV[i][2], accV[i][3]);
    }
  }
  __syncthreads();

  {  // M = I - P^T K ; B = Pv^T K  -> global   (Pv lives in Vs)
    float accM[4][4], accB[4][4];
#pragma unroll
    for (int i = 0; i < 4; ++i)
#pragma unroll
      for (int j = 0; j < 4; ++j) { accM[i][j] = 0.f; accB[i][j] = 0.f; }
#pragma unroll 4
    for (int s = 0; s < 64; ++s) {
      float4 pv  = *(const float4*)&As[s][i0];
      float4 pvv = *(const float4*)&Vs[s][i0];
      float4 kv  = *(const float4*)&Ks[s][j0];
      float pa[4] = {pv.x, pv.y, pv.z, pv.w};
      float qa[4] = {pvv.x, pvv.y, pvv.z, pvv.w};
      float ka[4] = {kv.x, kv.y, kv.z, kv.w};
#pragma unroll
      for (int i = 0; i < 4; ++i)
#pragma unroll
        for (int j = 0; j < 4; ++j) {
          accM[i][j] = fmaf(pa[i], ka[j], accM[i][j]);
          accB[i][j] = fmaf(qa[i], ka[j], accB[i][j]);
        }
    }
    const size_t base = (size_t)cb * 4096;
#pragma unroll
    for (int i = 0; i < 4; ++i) {
      float m0v = ((i0 + i) == (j0 + 0)) ? 1.f : 0.f;
      float m1v = ((i0 + i) == (j0 + 1)) ? 1.f : 0.f;
      float m2v = ((i0 + i) == (j0 + 2)) ? 1.f : 0.f;
      float m3v = ((i0 + i) == (j0 + 3)) ? 1.f : 0.f;
      *(float4*)&Mg[base + (size_t)(i0 + i) * 64 + j0] =
          make_float4(m0v - accM[i][0], m1v - accM[i][1],
                      m2v - accM[i][2], m3v - accM[i][3]);
      *(float4*)&Bg[base + (size_t)(i0 + i) * 64 + j0] =
          make_float4(accB[i][0], accB[i][1], accB[i][2], accB[i][3]);
    }
    const int fr = t >> 2, fc = (t & 3) << 4;
#pragma unroll
    for (int u = 0; u < 4; ++u)
      *(float4*)&Tg[base + (size_t)fr * 64 + fc + 4 * u] =
          *(const float4*)&Tt[fr][fc + 4 * u];
  }
}

// ---------------------------------------------------------------------------
// Phase 2 (parallel scan over chunks), v3: NGRP=8 groups x GSZ=4 chunks.
// p2a: 2048 single-wave blocks, M read straight from L2 (no LDS staging).
// p2b: 7-step cross-group scan. p2c: apply (g>=1, l=1..3).
// ---------------------------------------------------------------------------
__global__ __launch_bounds__(64, 1) void p2a_kernel(
    const float* __restrict__ Mg, const float* __restrict__ Bg,
    float* __restrict__ Mcum, float* __restrict__ Sall,
    float* __restrict__ BGfin) {
  __shared__ __align__(16) float Srow[2][4 * LD];  // ~2 KB
  const int bid  = blockIdx.x;
  const int g    = bid >> 8;           // group 0..7
  const int b    = (bid >> 5) & 7;     // batch
  const int w    = bid & 31;           // rowblock (0-15: M-part, 16-31: B-part)
  const int lane = threadIdx.x;
  const int rr   = lane >> 4;          // row within group of 4
  const int jc   = lane & 15;          // col group (4 cols)
  const bool isB = (w >= 16);
  const int n    = ((w & 15) << 2) + rr;  // row 0..63 within its matrix

  float4 cs;
  if (isB) cs = make_float4(0.f, 0.f, 0.f, 0.f);
  else
    cs = make_float4((jc * 4 + 0) == n ? 1.f : 0.f,
                     (jc * 4 + 1) == n ? 1.f : 0.f,
                     (jc * 4 + 2) == n ? 1.f : 0.f,
                     (jc * 4 + 3) == n ? 1.f : 0.f);

  for (int l = 0; l < GSZ; ++l) {
    const int c   = g * GSZ + l;
    const int cur = l & 1;
    const size_t cbase = ((size_t)c * BB + b) * 4096;
    // publish exclusive prefix (M-part skips l=0: identity, slot reused for MG)
    if (isB) *(float4*)&Sall[cbase + (size_t)n * 64 + jc * 4] = cs;
    else if (l > 0) *(float4*)&Mcum[cbase + (size_t)n * 64 + jc * 4] = cs;
    *(float4*)&Srow[cur][rr * LD + jc * 4] = cs;
    float4 bv = make_float4(0.f, 0.f, 0.f, 0.f);
    if (isB) bv = *(const float4*)&Bg[cbase + (size_t)n * 64 + jc * 4];

    const float* Mrow = Mg + cbase + jc * 4;  // L2-hot; 4-way lane broadcast
    float4 acc = make_float4(0.f, 0.f, 0.f, 0.f);
#pragma unroll
    for (int u = 0; u < 16; ++u) {
      float4 sv = *(const float4*)&Srow[cur][rr * LD + u * 4];
      float4 m0 = *(const float4*)&Mrow[(4 * u + 0) * 64];
      float4 m1 = *(const float4*)&Mrow[(4 * u + 1) * 64];
      float4 m2 = *(const float4*)&Mrow[(4 * u + 2) * 64];
      float4 m3 = *(const float4*)&Mrow[(4 * u + 3) * 64];
      acc.x = fmaf(sv.x, m0.x, acc.x); acc.y = fmaf(sv.x, m0.y, acc.y);
      acc.z = fmaf(sv.x, m0.z, acc.z); acc.w = fmaf(sv.x, m0.w, acc.w);
      acc.x = fmaf(sv.y, m1.x, acc.x); acc.y = fmaf(sv.y, m1.y, acc.y);
      acc.z = fmaf(sv.y, m1.z, acc.z); acc.w = fmaf(sv.y, m1.w, acc.w);
      acc.x = fmaf(sv.z, m2.x, acc.x); acc.y = fmaf(sv.z, m2.y, acc.y);
      acc.z = fmaf(sv.z, m2.z, acc.z); acc.w = fmaf(sv.z, m2.w, acc.w);
      acc.x = fmaf(sv.w, m3.x, acc.x); acc.y = fmaf(sv.w, m3.y, acc.y);
      acc.z = fmaf(sv.w, m3.z, acc.z); acc.w = fmaf(sv.w, m3.w, acc.w);
    }
    cs = make_float4(acc.x + bv.x, acc.y + bv.y, acc.z + bv.z, acc.w + bv.w);
  }
  // inclusive group finals: MG -> Mcum's l=0 slot; BG -> BGfin scratch
  if (isB)
    *(float4*)&BGfin[((size_t)g * BB + b) * 4096 + (size_t)n * 64 + jc * 4] = cs;
  else
    *(float4*)&Mcum[((size_t)(g * GSZ) * BB + b) * 4096 + (size_t)n * 64 + jc * 4] = cs;
}

__global__ __launch_bounds__(64, 1) void p2b_kernel(
    const float* __restrict__ Mcum, const float* __restrict__ BGfin,
    float* __restrict__ Sall) {
  __shared__ __align__(16) float Srow[2][4 * LD];
  const int bid  = blockIdx.x;
  const int b    = bid >> 4;           // batch
  const int w    = bid & 15;           // row group
  const int lane = threadIdx.x;
  const int rr   = lane >> 4;
  const int jc   = lane & 15;
  const int n    = w * 4 + rr;

  float4 cs = make_float4(0.f, 0.f, 0.f, 0.f);

  for (int g2 = 0; g2 < NGRP - 1; ++g2) {
    const int cur = g2 & 1;
    *(float4*)&Srow[cur][rr * LD + jc * 4] = cs;
    float4 bv = *(const float4*)&BGfin[((size_t)g2 * BB + b) * 4096 +
                                       (size_t)n * 64 + jc * 4];
    // MGfin for group g2 lives in Mcum's chunk-(g2*GSZ) slot
    const float* Mrow =
        Mcum + ((size_t)(g2 * GSZ) * BB + b) * 4096 + jc * 4;
    float4 acc = make_float4(0.f, 0.f, 0.f, 0.f);
#pragma unroll
    for (int u = 0; u < 16; ++u) {
      float4 sv = *(const float4*)&Srow[cur][rr * LD + u * 4];
      float4 m0 = *(const float4*)&Mrow[(4 * u + 0) * 64];
      float4 m1 = *(const float4*)&Mrow[(4 * u + 1) * 64];
      float4 m2 = *(const float4*)&Mrow[(4 * u + 2) * 64];
      float4 m3 = *(const float4*)&Mrow[(4 * u + 3) * 64];
      acc.x = fmaf(sv.x, m0.x, acc.x); acc.y = fmaf(sv.x, m0.y, acc.y);
      acc.z = fmaf(sv.x, m0.z, acc.z); acc.w = fmaf(sv.x, m0.w, acc.w);
      acc.x = fmaf(sv.y, m1.x, acc.x); acc.y = fmaf(sv.y, m1.y, acc.y);
      acc.z = fmaf(sv.y, m1.z, acc.z); acc.w = fmaf(sv.y, m1.w, acc.w);
      acc.x = fmaf(sv.z, m2.x, acc.x); acc.y = fmaf(sv.z, m2.y, acc.y);
      acc.z = fmaf(sv.z, m2.z, acc.z); acc.w = fmaf(sv.z, m2.w, acc.w);
      acc.x = fmaf(sv.w, m3.x, acc.x); acc.y = fmaf(sv.w, m3.y, acc.y);
      acc.z = fmaf(sv.w, m3.z, acc.z); acc.w = fmaf(sv.w, m3.w, acc.w);
    }
    cs = make_float4(acc.x + bv.x, acc.y + bv.y, acc.z + bv.z, acc.w + bv.w);
    // S_{g2+1} -> Sall at that group's first chunk (l=0 slot)
    *(float4*)&Sall[((size_t)((g2 + 1) * GSZ) * BB + b) * 4096 +
                    (size_t)n * 64 + jc * 4] = cs;
  }
}

__global__ __launch_bounds__(256) void p2c_kernel(
    const float* __restrict__ Mcum, float* __restrict__ Sall) {
  __shared__ __align__(16) float SgT[64][LD];  // S_g transposed
  __shared__ __align__(16) float Mc[64][LD];
  const int idx = blockIdx.x;        // 0..167
  const int b   = idx & 7;
  const int q   = idx >> 3;          // 0..20
  const int g   = 1 + q / (GSZ - 1);
  const int l   = 1 + q % (GSZ - 1);
  const int c   = g * GSZ + l;
  const int t   = threadIdx.x;
  const size_t cbase = ((size_t)c * BB + b) * 4096;
  const size_t gbase = ((size_t)(g * GSZ) * BB + b) * 4096;
  {
    const int tau = t & 63, c0 = (t >> 6) << 4;  // 4 col-blocks of 16
    const float* sgp = Sall + gbase + (size_t)tau * 64 + c0;
    const float* mcp = Mcum + cbase + (size_t)tau * 64 + c0;
#pragma unroll
    for (int u = 0; u < 4; ++u) {
      float4 sv = *(const float4*)&sgp[4 * u];
      SgT[c0 + 4 * u + 0][tau] = sv.x;
      SgT[c0 + 4 * u + 1][tau] = sv.y;
      SgT[c0 + 4 * u + 2][tau] = sv.z;
      SgT[c0 + 4 * u + 3][tau] = sv.w;
      *(float4*)&Mc[tau][c0 + 4 * u] = *(const float4*)&mcp[4 * u];
    }
  }
  __syncthreads();
  const int i0 = (t >> 4) << 2;
  const int j0 = (t & 15) << 2;
  float acc[4][4];
#pragma unroll
  for (int i = 0; i < 4; ++i)
#pragma unroll
    for (int j = 0; j < 4; ++j) acc[i][j] = 0.f;
  for (int m = 0; m < 64; ++m) {
    float4 tv = *(const float4*)&SgT[m][i0];
    float4 kv = *(const float4*)&Mc[m][j0];
    float ta[4] = {tv.x, tv.y, tv.z, tv.w};
    float ka[4] = {kv.x, kv.y, kv.z, kv.w};
#pragma unroll
    for (int i = 0; i < 4; ++i)
#pragma unroll
      for (int j = 0; j < 4; ++j) acc[i][j] = fmaf(ta[i], ka[j], acc[i][j]);
  }
  float* dst = Sall + cbase;
#pragma unroll
  for (int i = 0; i < 4; ++i) {
    float4 d = *(float4*)&dst[(size_t)(i0 + i) * 64 + j0];
    d.x += acc[i][0]; d.y += acc[i][1];
    d.z += acc[i][2]; d.w += acc[i][3];
    *(float4*)&dst[(size_t)(i0 + i) * 64 + j0] = d;
  }
}

// ---------------------------------------------------------------------------
// Phase 3: Gt = (Q K^T)^T ; W = V - K S0^T ; U = T W ;
//   Y = Q S0^T + tril(G) U ; y = tanh(Y) * sigmoid(Z)  -> ys (f16)
// v2: 4 LDS arrays (69.6 KB -> 2 blocks/CU). The Ks slot is sequentially
// reused Ks -> W -> U (each overwrite after full-register accumulate +
// barrier). Tt is read directly from global in the U stage (16 KB/block,
// L2/L3-hot, 16-lane broadcast per quad — same pattern as p2a's M reads).
// ---------------------------------------------------------------------------
__global__ __launch_bounds__(256) void phase3_kernel(
    const float* __restrict__ kvqz, const float* __restrict__ Tg,
    const float* __restrict__ Sall, _Float16* __restrict__ ys) {
  __shared__ __align__(16) float Ks[64][LD];   // K, then W, then U
  __shared__ __align__(16) float Qs[64][LD];
  __shared__ __align__(16) float S0s[64][LD];
  __shared__ __align__(16) float Gts[64][LD];
  const int cb = blockIdx.x;
  const int c  = cb >> 3, b = cb & 7;
  const int t  = threadIdx.x;
  const size_t base = (size_t)cb * 4096;

  {
    const int tau = t >> 2, m0 = (t & 3) << 4;
    const float* src = kvqz + (size_t)((c * 64 + tau) * BB + b) * 256;
#pragma unroll
    for (int u = 0; u < 4; ++u) {
      *(float4*)&Ks[tau][m0 + 4 * u]  = *(const float4*)&src[m0 + 4 * u];
      *(float4*)&Qs[tau][m0 + 4 * u]  = *(const float4*)&src[128 + m0 + 4 * u];
      *(float4*)&S0s[tau][m0 + 4 * u] = *(const float4*)&Sall[base + (size_t)tau * 64 + m0 + 4 * u];
    }
  }
  __syncthreads();

  const int i0 = (t >> 4) << 2;
  const int j0 = (t & 15) << 2;

  {  // Gt[s][tq] = sum_m K[s][m] Q[tq][m]  -> Gts
    float acc[4][4];
#pragma unroll
    for (int i = 0; i < 4; ++i)
#pragma unroll
      for (int j = 0; j < 4; ++j) acc[i][j] = 0.f;
#pragma unroll 2
    for (int m4 = 0; m4 < 64; m4 += 4) {
      float4 kr[4], qr[4];
#pragma unroll
      for (int i = 0; i < 4; ++i) kr[i] = *(const float4*)&Ks[i0 + i][m4];
#pragma unroll
      for (int j = 0; j < 4; ++j) qr[j] = *(const float4*)&Qs[j0 + j][m4];
#pragma unroll
      for (int i = 0; i < 4; ++i)
#pragma unroll
        for (int j = 0; j < 4; ++j) acc[i][j] += dot4(kr[i], qr[j]);
    }
#pragma unroll
    for (int i = 0; i < 4; ++i)
      *(float4*)&Gts[i0 + i][j0] =
          make_float4(acc[i][0], acc[i][1], acc[i][2], acc[i][3]);
  }

  {  // W[tau][n] = V[tau][n] - sum_m K[tau][m] S0[n][m]  -> Ks slot
    float acc[4][4];
#pragma unroll
    for (int i = 0; i < 4; ++i) {
      const float* vrow = kvqz + (size_t)((c * 64 + i0 + i) * BB + b) * 256 + 64;
      float4 vv = *(const float4*)&vrow[j0];
      acc[i][0] = vv.x; acc[i][1] = vv.y; acc[i][2] = vv.z; acc[i][3] = vv.w;
    }
#pragma unroll 2
    for (int m4 = 0; m4 < 64; m4 += 4) {
      float4 kr[4], sr[4];
#pragma unroll
      for (int i = 0; i < 4; ++i) kr[i] = *(const float4*)&Ks[i0 + i][m4];
#pragma unroll
      for (int j = 0; j < 4; ++j) sr[j] = *(const float4*)&S0s[j0 + j][m4];
#pragma unroll
      for (int i = 0; i < 4; ++i)
#pragma unroll
        for (int j = 0; j < 4; ++j) acc[i][j] -= dot4(kr[i], sr[j]);
    }
    __syncthreads();   // all reads of Ks (stages 1+2) complete
#pragma unroll
    for (int i = 0; i < 4; ++i)
      *(float4*)&Ks[i0 + i][j0] =
          make_float4(acc[i][0], acc[i][1], acc[i][2], acc[i][3]);
  }
  __syncthreads();

  float4 zv[4];
  {  // U[tq][n] = sum_s Tt[s][tq] W[s][n]  (Tt from global; W in Ks slot)
#pragma unroll
    for (int i = 0; i < 4; ++i) {
      const float* zrow = kvqz + (size_t)((c * 64 + i0 + i) * BB + b) * 256 + 192;
      zv[i] = *(const float4*)&zrow[j0];
    }
    float acc[4][4];
#pragma unroll
    for (int i = 0; i < 4; ++i)
#pragma unroll
      for (int j = 0; j < 4; ++j) acc[i][j] = 0.f;
    const float* Tp = Tg + base + i0;
#pragma unroll 4
    for (int s = 0; s < 64; ++s) {
      float4 tv = *(const float4*)&Tp[(size_t)s * 64];   // broadcast per quad
      float4 wv = *(const float4*)&Ks[s][j0];
      float ta[4] = {tv.x, tv.y, tv.z, tv.w};
      float wa[4] = {wv.x, wv.y, wv.z, wv.w};
#pragma unroll
      for (int i = 0; i < 4; ++i)
#pragma unroll
        for (int j = 0; j < 4; ++j) acc[i][j] = fmaf(ta[i], wa[j], acc[i][j]);
    }
    __syncthreads();   // all reads of W complete before overwrite
#pragma unroll
    for (int i = 0; i < 4; ++i)
      *(float4*)&Ks[i0 + i][j0] =
          make_float4(acc[i][0], acc[i][1], acc[i][2], acc[i][3]);
  }
  __syncthreads();

  {  // Y = Q S0^T + tril(G) U ; out (f16)   (U in Ks slot)
    float acc[4][4];
#pragma unroll
    for (int i = 0; i < 4; ++i)
#pragma unroll
      for (int j = 0; j < 4; ++j) acc[i][j] = 0.f;
#pragma unroll 2
    for (int m4 = 0; m4 < 64; m4 += 4) {
      float4 qr[4], sr[4];
#pragma unroll
      for (int i = 0; i < 4; ++i) qr[i] = *(const float4*)&Qs[i0 + i][m4];
#pragma unroll
      for (int j = 0; j < 4; ++j) sr[j] = *(const float4*)&S0s[j0 + j][m4];
#pragma unroll
      for (int i = 0; i < 4; ++i)
#pragma unroll
        for (int j = 0; j < 4; ++j) acc[i][j] += dot4(qr[i], sr[j]);
    }
#pragma unroll 4
    for (int s = 0; s < 64; ++s) {
      float4 gv = *(const float4*)&Gts[s][i0];
      float4 uv = *(const float4*)&Ks[s][j0];
      float ga[4] = {gv.x, gv.y, gv.z, gv.w};
      float ua[4] = {uv.x, uv.y, uv.z, uv.w};
#pragma unroll
      for (int i = 0; i < 4; ++i) {
        float gi = (s <= i0 + i) ? ga[i] : 0.f;
#pragma unroll
        for (int j = 0; j < 4; ++j) acc[i][j] = fmaf(gi, ua[j], acc[i][j]);
      }
    }
#pragma unroll
    for (int i = 0; i < 4; ++i) {
      float za[4] = {zv[i].x, zv[i].y, zv[i].z, zv[i].w};
      _Float16 oh[4];
#pragma unroll
      for (int j = 0; j < 4; ++j) {
        float e2 = __expf(2.f * acc[i][j]);
        float th = 1.f - 2.f / (e2 + 1.f);
        float sg = 1.f / (1.f + __expf(-za[j]));
        oh[j] = (_Float16)(th * sg);
      }
      half4h o4 = {oh[0], oh[1], oh[2], oh[3]};
      *(half4h*)&ys[(size_t)((c * 64 + i0 + i) * BB + b) * 64 + j0] = o4;
    }
  }
}

// ---------------------------------------------------------------------------
extern "C" void kernel_launch(void* const* d_in, const int* in_sizes, int n_in,
                              void* d_out, int out_size, void* d_ws, size_t ws_size,
                              hipStream_t stream) {
  const float* x    = (const float*)d_in[0];
  const float* Win  = (const float*)d_in[1];
  const float* Wk   = (const float*)d_in[2];
  const float* Wv   = (const float*)d_in[3];
  const float* Wq   = (const float*)d_in[4];
  const float* Wz   = (const float*)d_in[5];
  const float* Wout = (const float*)d_in[6];
  float* out = (float*)d_out;

  char* ws = (char*)d_ws;
  // Liveness-checked layout (fp32 unless noted):
  //   [0,1M):    Wfh (f16, [0,512K); fuse_reduce -> kvqz GEMM), then
  //              BGfin (1M; p2a -> p2b), then Woh (f16, [0,128K); cvt AFTER
  //              p2b/p2c -> final GEMM).  Strictly sequential.
  //   [1M,17M):  kvqz (kvqz GEMM -> phase3).
  //   [17M,21M): Mcum (p2a -> p2c; l=0 slots carry MGfin for p2b);
  //              ysh (f16) [17M,19M) (phase3 -> final GEMM, after Mcum dead).
  //   [21M,37M): Pg (fuse_gemm -> fuse_reduce); then xh (f16; cvt -> kvqz
  //              GEMM, [21M,53M) if ws>=53MB else 16MB halves); then
  //              Tg/Mg/Bg/Sall (phase1 -> phase3).
  _Float16* Wfh  = (_Float16*)(ws);
  float* BGfin   = (float*)(ws);              // written by p2a (Wfh dead)
  _Float16* Woh  = (_Float16*)(ws);           // written after p2b (BGfin dead)
  float* kvqz    = (float*)(ws + (1u  << 20));
  _Float16* ysh  = (_Float16*)(ws + (17u << 20));
  float* Mcum    = (float*)(ws + (17u << 20));
  float* Tg      = (float*)(ws + (21u << 20));
  float* Mg      = (float*)(ws + (25u << 20));
  float* Bg      = (float*)(ws + (29u << 20));
  float* Sall    = (float*)(ws + (33u << 20));
  float* Pg      = (float*)(ws + (21u << 20));
  _Float16* xh   = (_Float16*)(ws + (21u << 20));

  fuse_gemm_kernel<<<dim3(DIM_ / 128, 2, KSPL), 256, 0, stream>>>(Wk, Wv, Wq, Wz, Win, Pg);
  fuse_reduce_kernel<<<(256 * DIM_ / 4) / 256, 256, 0, stream>>>(Pg, Wfh);

  if (ws_size >= (53ull << 20)) {
    cvt_f16_kernel<<<2048, 256, 0, stream>>>(x, xh, (long)MR_ * DIM_ / 8);
    gemm_h16<<<dim3(256 / 64, MR_ / 64), 256, 0, stream>>>(xh, Wfh, kvqz, MR_, 256, DIM_);
  } else {
    const long half_rows = MR_ / 2;
    for (int h = 0; h < 2; ++h) {
      const float* xs = x + (size_t)h * half_rows * DIM_;
      float* cs = kvqz + (size_t)h * half_rows * 256;
      cvt_f16_kernel<<<2048, 256, 0, stream>>>(xs, xh, half_rows * DIM_ / 8);
      gemm_h16<<<dim3(256 / 64, (int)(half_rows / 64)), 256, 0, stream>>>(
          xh, Wfh, cs, (int)half_rows, 256, DIM_);
    }
  }

  norm_k_kernel<<<MR_ / 4, 256, 0, stream>>>(kvqz);
  phase1_kernel<<<NCH * BB, 256, 0, stream>>>(kvqz, Tg, Mg, Bg);
  p2a_kernel<<<NGRP * BB * 32, 64, 0, stream>>>(Mg, Bg, Mcum, Sall, BGfin);
  p2b_kernel<<<16 * BB, 64, 0, stream>>>(Mcum, BGfin, Sall);
  p2c_kernel<<<(NGRP - 1) * (GSZ - 1) * BB, 256, 0, stream>>>(Mcum, Sall);
  // Wout -> f16 AFTER p2b: [0,128K) is free (Wfh and BGfin both dead).
  cvt_f16_kernel<<<32, 256, 0, stream>>>(Wout, Woh, (long)(DIM_ * NS_ / 8));
  phase3_kernel<<<NCH * BB, 256, 0, stream>>>(kvqz, Tg, Sall, ysh);
  gemm_h16<<<dim3(DIM_ / 64, MR_ / 64), 256, 0, stream>>>(ysh, Woh, out, MR_, DIM_, NS_);
}

// Round 10
// 269.252 us; speedup vs baseline: 1.0574x; 1.0574x over previous
//
#include <hip/hip_runtime.h>
#include <math.h>

#define TT   2048
#define BB   8
#define DIM_ 1024
#define DI_  2048
#define NS_  64
#define MR_  (TT * BB)   // 16384 rows (t-major, b-minor)
#define NCH  32          // chunks of 64 steps
#define LD   68          // padded LDS leading dim (16B-aligned rows)
#define NGRP 8           // scan groups
#define GSZ  4           // chunks per group (NGRP*GSZ == NCH)
#define LDH2 40          // padded f16 LDS stride for gemm_h16 (80 B rows)
#define FKS  4           // fuse GEMM split-K factor

typedef _Float16 half8 __attribute__((ext_vector_type(8)));
typedef _Float16 half4h __attribute__((ext_vector_type(4)));
typedef float floatx4 __attribute__((ext_vector_type(4)));

__device__ __forceinline__ float dot4(float4 a, float4 b) {
  return a.x * b.x + a.y * b.y + a.z * b.z + a.w * b.w;
}

__device__ __forceinline__ half8 cvt8(float4 lo, float4 hi) {
  half8 h = {(_Float16)lo.x, (_Float16)lo.y, (_Float16)lo.z, (_Float16)lo.w,
             (_Float16)hi.x, (_Float16)hi.y, (_Float16)hi.z, (_Float16)hi.w};
  return h;
}

// ---------------------------------------------------------------------------
// fp32 -> f16 elementwise convert (n8 groups of 8 elems), grid-stride.
// ---------------------------------------------------------------------------
__global__ __launch_bounds__(256) void cvt_f16_kernel(
    const float* __restrict__ in, _Float16* __restrict__ out, long n8) {
  long i = (long)blockIdx.x * 256 + threadIdx.x;
  const long stride = (long)gridDim.x * 256;
  for (; i < n8; i += stride) {
    const float4 lo = *(const float4*)&in[i * 8];
    const float4 hi = *(const float4*)&in[i * 8 + 4];
    *(half8*)&out[i * 8] = cvt8(lo, hi);
  }
}

// ---------------------------------------------------------------------------
// Pack Wk/Wv/Wq/Wz (each [64][2048] fp32) into contiguous f16 [256][2048].
// ---------------------------------------------------------------------------
__global__ __launch_bounds__(256) void pack_wg_kernel(
    const float* __restrict__ Wk, const float* __restrict__ Wv,
    const float* __restrict__ Wq, const float* __restrict__ Wz,
    _Float16* __restrict__ Wgh) {
  const float* Wg[4] = {Wk, Wv, Wq, Wz};
  const long g = (long)blockIdx.x * 256 + threadIdx.x;  // [0, 65536)
  const int row = (int)(g >> 8);          // g*8/2048
  const int k   = (int)((g & 255) << 3);
  const float* src = Wg[row >> 6] + (size_t)(row & 63) * DI_ + k;
  const float4 lo = *(const float4*)&src[0];
  const float4 hi = *(const float4*)&src[4];
  *(half8*)&Wgh[(size_t)row * DI_ + k] = cvt8(lo, hi);
}

// ---------------------------------------------------------------------------
// Transpose+convert: Win[2048][1024] fp32 -> WinTh[1024][2048] f16.
// 64x64 LDS tiles; grid (cols/64=16, rows/64=32).
// ---------------------------------------------------------------------------
__global__ __launch_bounds__(256) void transpose_win_kernel(
    const float* __restrict__ Win, _Float16* __restrict__ WinTh) {
  __shared__ float T[64][65];
  const int t  = threadIdx.x;
  const int c0 = blockIdx.x * 64;   // Win col base (0..1023)
  const int r0 = blockIdx.y * 64;   // Win row base (0..2047)
  {
    const int tr = t >> 2, tc = (t & 3) * 16;
#pragma unroll
    for (int u = 0; u < 4; ++u) {
      float4 v = *(const float4*)&Win[(size_t)(r0 + tr) * DIM_ + c0 + tc + 4 * u];
      T[tr][tc + 4 * u + 0] = v.x;
      T[tr][tc + 4 * u + 1] = v.y;
      T[tr][tc + 4 * u + 2] = v.z;
      T[tr][tc + 4 * u + 3] = v.w;
    }
  }
  __syncthreads();
  {
    const int oc = t >> 2;            // out row within tile (= Win col)
    const int orr = (t & 3) * 16;     // out col base (= Win row)
    _Float16 h[16];
#pragma unroll
    for (int u = 0; u < 16; ++u) h[u] = (_Float16)T[orr + u][oc];
    _Float16* dst = WinTh + (size_t)(c0 + oc) * DI_ + r0 + orr;
    *(half8*)&dst[0] = *(half8*)&h[0];
    *(half8*)&dst[8] = *(half8*)&h[8];
  }
}

// ---------------------------------------------------------------------------
// f16 MFMA GEMM: C[M,N] = A[M,K] * B[N,K]^T, A/B already f16 row-major.
// BM=64 x BN=64 tile, BK=32, 4 waves in 2x2 (wave tile 32x32, 2x2 MFMA).
// ---------------------------------------------------------------------------
__global__ __launch_bounds__(256) void gemm_h16(
    const _Float16* __restrict__ A, const _Float16* __restrict__ B,
    float* __restrict__ C, int M, int N, int K) {
  __shared__ __align__(16) _Float16 Ah[2][64 * LDH2];  // 2 x 5 KB
  __shared__ __align__(16) _Float16 Bh[2][64 * LDH2];  // 2 x 5 KB
  const int tid  = threadIdx.x;
  const int m0   = blockIdx.y * 64;
  const int n0   = blockIdx.x * 64;
  const int wave = tid >> 6, lane = tid & 63;
  const int wm   = (wave >> 1) * 32;   // wave row base (0/32)
  const int wn   = (wave & 1) * 32;    // wave col base (0/32)
  const int quad = lane >> 4, l16 = lane & 15;
  const int srow = tid >> 2;           // stage row 0..63
  const int scol = (tid & 3) * 8;      // stage k-offset (f16 elems)

  const _Float16* Ap = A + (size_t)(m0 + srow) * K + scol;
  const _Float16* Bp = B + (size_t)(n0 + srow) * K + scol;

  floatx4 acc[2][2];
#pragma unroll
  for (int i = 0; i < 2; ++i)
#pragma unroll
    for (int j = 0; j < 2; ++j) acc[i][j] = (floatx4)0.f;

  half8 ha, hb;
  ha = *(const half8*)(Ap);
  hb = *(const half8*)(Bp);
  *(half8*)&Ah[0][srow * LDH2 + scol] = ha;
  *(half8*)&Bh[0][srow * LDH2 + scol] = hb;
  __syncthreads();

  const int NK = K >> 5;
  for (int kt = 0; kt < NK; ++kt) {
    const int cur = kt & 1;
    if (kt + 1 < NK) {
      ha = *(const half8*)(Ap + (kt + 1) * 32);
      hb = *(const half8*)(Bp + (kt + 1) * 32);
    }
    half8 af[2], bf[2];
#pragma unroll
    for (int mt = 0; mt < 2; ++mt)
      af[mt] = *(const half8*)&Ah[cur][(wm + mt * 16 + l16) * LDH2 + quad * 8];
#pragma unroll
    for (int nt = 0; nt < 2; ++nt)
      bf[nt] = *(const half8*)&Bh[cur][(wn + nt * 16 + l16) * LDH2 + quad * 8];
#pragma unroll
    for (int mt = 0; mt < 2; ++mt)
#pragma unroll
      for (int nt = 0; nt < 2; ++nt)
        acc[mt][nt] = __builtin_amdgcn_mfma_f32_16x16x32_f16(
            af[mt], bf[nt], acc[mt][nt], 0, 0, 0);
    if (kt + 1 < NK) {
      const int nxt = cur ^ 1;
      *(half8*)&Ah[nxt][srow * LDH2 + scol] = ha;
      *(half8*)&Bh[nxt][srow * LDH2 + scol] = hb;
    }
    __syncthreads();
  }

#pragma unroll
  for (int mt = 0; mt < 2; ++mt) {
#pragma unroll
    for (int i = 0; i < 4; ++i) {
      const size_t r = (size_t)(m0 + wm + mt * 16 + quad * 4 + i) * N;
#pragma unroll
      for (int nt = 0; nt < 2; ++nt)
        C[r + n0 + wn + nt * 16 + l16] = acc[mt][nt][i];
    }
  }
}

// Split-K variant: blockIdx.z selects a K-chunk; partial to Cp[z][M][N].
__global__ __launch_bounds__(256) void gemm_h16_splitk(
    const _Float16* __restrict__ A, const _Float16* __restrict__ B,
    float* __restrict__ Cp, int M, int N, int K, int kchunk) {
  __shared__ __align__(16) _Float16 Ah[2][64 * LDH2];
  __shared__ __align__(16) _Float16 Bh[2][64 * LDH2];
  const int tid  = threadIdx.x;
  const int m0   = blockIdx.y * 64;
  const int n0   = blockIdx.x * 64;
  const int kb   = blockIdx.z * kchunk;
  const int wave = tid >> 6, lane = tid & 63;
  const int wm   = (wave >> 1) * 32;
  const int wn   = (wave & 1) * 32;
  const int quad = lane >> 4, l16 = lane & 15;
  const int srow = tid >> 2;
  const int scol = (tid & 3) * 8;

  const _Float16* Ap = A + (size_t)(m0 + srow) * K + kb + scol;
  const _Float16* Bp = B + (size_t)(n0 + srow) * K + kb + scol;
  float* C = Cp + (size_t)blockIdx.z * M * N;

  floatx4 acc[2][2];
#pragma unroll
  for (int i = 0; i < 2; ++i)
#pragma unroll
    for (int j = 0; j < 2; ++j) acc[i][j] = (floatx4)0.f;

  half8 ha, hb;
  ha = *(const half8*)(Ap);
  hb = *(const half8*)(Bp);
  *(half8*)&Ah[0][srow * LDH2 + scol] = ha;
  *(half8*)&Bh[0][srow * LDH2 + scol] = hb;
  __syncthreads();

  const int NK = kchunk >> 5;
  for (int kt = 0; kt < NK; ++kt) {
    const int cur = kt & 1;
    if (kt + 1 < NK) {
      ha = *(const half8*)(Ap + (kt + 1) * 32);
      hb = *(const half8*)(Bp + (kt + 1) * 32);
    }
    half8 af[2], bf[2];
#pragma unroll
    for (int mt = 0; mt < 2; ++mt)
      af[mt] = *(const half8*)&Ah[cur][(wm + mt * 16 + l16) * LDH2 + quad * 8];
#pragma unroll
    for (int nt = 0; nt < 2; ++nt)
      bf[nt] = *(const half8*)&Bh[cur][(wn + nt * 16 + l16) * LDH2 + quad * 8];
#pragma unroll
    for (int mt = 0; mt < 2; ++mt)
#pragma unroll
      for (int nt = 0; nt < 2; ++nt)
        acc[mt][nt] = __builtin_amdgcn_mfma_f32_16x16x32_f16(
            af[mt], bf[nt], acc[mt][nt], 0, 0, 0);
    if (kt + 1 < NK) {
      const int nxt = cur ^ 1;
      *(half8*)&Ah[nxt][srow * LDH2 + scol] = ha;
      *(half8*)&Bh[nxt][srow * LDH2 + scol] = hb;
    }
    __syncthreads();
  }

#pragma unroll
  for (int mt = 0; mt < 2; ++mt) {
#pragma unroll
    for (int i = 0; i < 4; ++i) {
      const size_t r = (size_t)(m0 + wm + mt * 16 + quad * 4 + i) * N;
#pragma unroll
      for (int nt = 0; nt < 2; ++nt)
        C[r + n0 + wn + nt * 16 + l16] = acc[mt][nt][i];
    }
  }
}

// Wfh[i] = (f16) sum_{z<FKS} Pg4[z][i]
__global__ __launch_bounds__(256) void fuse_reduce4_kernel(
    const float* __restrict__ Pg4, _Float16* __restrict__ Wfh) {
  const size_t i = ((size_t)blockIdx.x * 256 + threadIdx.x) << 2;
  float4 s = *(const float4*)&Pg4[i];
#pragma unroll
  for (int z = 1; z < FKS; ++z) {
    float4 p = *(const float4*)&Pg4[(size_t)z * (256 * DIM_) + i];
    s.x += p.x; s.y += p.y; s.z += p.z; s.w += p.w;
  }
  half4h h = {(_Float16)s.x, (_Float16)s.y, (_Float16)s.z, (_Float16)s.w};
  *(half4h*)&Wfh[i] = h;
}

// ---------------------------------------------------------------------------
// Phase 1: per chunk-batch:  A = K K^T ; Tt = inv(I+stril(A)) (transposed);
// P = T K ; Pv = T V ; M = I - P^T K ; B = Pv^T K.  Store Tt, M, B.
// K rows unit-normalized on load (norm_k folded in; identical in phase3).
// A=KK^T gather remapped to consecutive-row reads (conflict-free).
// ---------------------------------------------------------------------------
__global__ __launch_bounds__(256) void phase1_kernel(
    const float* __restrict__ kvqz, float* __restrict__ Tg,
    float* __restrict__ Mg, float* __restrict__ Bg) {
  __shared__ __align__(16) float Ks[64][LD];
  __shared__ __align__(16) float Vs[64][LD];   // V, then Pv
  __shared__ __align__(16) float As[64][LD];   // A=KK^T, then P
  __shared__ __align__(16) float Tt[64][LD];
  const int cb = blockIdx.x;
  const int c  = cb >> 3, b = cb & 7;
  const int t  = threadIdx.x;

  {
    const int tau = t >> 2, m0q = (t & 3) << 4;
    const float* src = kvqz + (size_t)((c * 64 + tau) * BB + b) * 256;
    float4 kv[4];
    float ss = 0.f;
#pragma unroll
    for (int u = 0; u < 4; ++u) {
      kv[u] = *(const float4*)&src[m0q + 4 * u];
      ss += dot4(kv[u], kv[u]);
      *(float4*)&Vs[tau][m0q + 4 * u] = *(const float4*)&src[64 + m0q + 4 * u];
    }
    ss += __shfl_xor(ss, 1);
    ss += __shfl_xor(ss, 2);
    const float sc = 1.f / (sqrtf(ss) + 1e-6f);
#pragma unroll
    for (int u = 0; u < 4; ++u) {
      kv[u].x *= sc; kv[u].y *= sc; kv[u].z *= sc; kv[u].w *= sc;
      *(float4*)&Ks[tau][m0q + 4 * u] = kv[u];
    }
  }
  __syncthreads();

  const int i0 = (t >> 4) << 2;
  const int j0 = (t & 15) << 2;
  const int jc = t & 15;

  {  // A = K K^T  (cols jc+16*jj: consecutive-row gather, 2-way = free)
    float acc[4][4];
#pragma unroll
    for (int i = 0; i < 4; ++i)
#pragma unroll
      for (int j = 0; j < 4; ++j) acc[i][j] = 0.f;
#pragma unroll 2
    for (int m4 = 0; m4 < 64; m4 += 4) {
      float4 ar[4], br[4];
#pragma unroll
      for (int i = 0; i < 4; ++i) ar[i] = *(const float4*)&Ks[i0 + i][m4];
#pragma unroll
      for (int j = 0; j < 4; ++j) br[j] = *(const float4*)&Ks[jc + 16 * j][m4];
#pragma unroll
      for (int i = 0; i < 4; ++i)
#pragma unroll
        for (int j = 0; j < 4; ++j) acc[i][j] += dot4(ar[i], br[j]);
    }
#pragma unroll
    for (int i = 0; i < 4; ++i)
#pragma unroll
      for (int j = 0; j < 4; ++j) As[i0 + i][jc + 16 * j] = acc[i][j];
  }
  __syncthreads();

  if (t < 64) {  // register forward substitution (fully unrolled, tt in VGPRs)
    const int j = t;
    float tt[64];
    tt[0] = (j == 0) ? 1.f : 0.f;
#pragma unroll
    for (int i = 1; i < 64; ++i) {
      float p0 = 0.f, p1 = 0.f, p2 = 0.f, p3 = 0.f;
      const int nf = i >> 2;
#pragma unroll
      for (int s4 = 0; s4 < nf; ++s4) {
        float4 av = *(const float4*)&As[i][4 * s4];   // broadcast (uniform)
        p0 = fmaf(av.x, tt[4 * s4 + 0], p0);
        p1 = fmaf(av.y, tt[4 * s4 + 1], p1);
        p2 = fmaf(av.z, tt[4 * s4 + 2], p2);
        p3 = fmaf(av.w, tt[4 * s4 + 3], p3);
      }
#pragma unroll
      for (int s = 4 * nf; s < i; ++s) p0 = fmaf(As[i][s], tt[s], p0);
      tt[i] = (i == j) ? 1.f : -((p0 + p1) + (p2 + p3));
    }
#pragma unroll
    for (int u = 0; u < 16; ++u)
      *(float4*)&Tt[j][4 * u] = make_float4(tt[4 * u + 0], tt[4 * u + 1],
                                            tt[4 * u + 2], tt[4 * u + 3]);
  }
  __syncthreads();

  {  // P = T K -> As ; Pv = T V -> Vs (barrier before overwrite)
    float accP[4][4], accV[4][4];
#pragma unroll
    for (int i = 0; i < 4; ++i)
#pragma unroll
      for (int j = 0; j < 4; ++j) { accP[i][j] = 0.f; accV[i][j] = 0.f; }
#pragma unroll 4
    for (int s = 0; s < 64; ++s) {
      float4 tv = *(const float4*)&Tt[s][i0];
      float4 kv = *(const float4*)&Ks[s][j0];
      float4 vv = *(const float4*)&Vs[s][j0];
      float ta[4] = {tv.x, tv.y, tv.z, tv.w};
      float ka[4] = {kv.x, kv.y, kv.z, kv.w};
      float va[4] = {vv.x, vv.y, vv.z, vv.w};
#pragma unroll
      for (int i = 0; i < 4; ++i)
#pragma unroll
        for (int j = 0; j < 4; ++j) {
          accP[i][j] = fmaf(ta[i], ka[j], accP[i][j]);
          accV[i][j] = fmaf(ta[i], va[j], accV[i][j]);
        }
    }
    __syncthreads();
#pragma unroll
    for (int i = 0; i < 4; ++i) {
      *(float4*)&As[i0 + i][j0] =
          make_float4(accP[i][0], accP[i][1], accP[i][2], accP[i][3]);
      *(float4*)&Vs[i0 + i][j0] =
          make_float4(accV[i][0], accV[i][1], accV[i][2], accV[i][3]);
    }
  }
  __syncthreads();

  {  // M = I - P^T K ; B = Pv^T K  -> global   (Pv lives in Vs)
    float accM[4][4], accB[4][4];
#pragma unroll
    for (int i = 0; i < 4; ++i)
#pragma unroll
      for (int j = 0; j < 4; ++j) { accM[i][j] = 0.f; accB[i][j] = 0.f; }
#pragma unroll 4
    for (int s = 0; s < 64; ++s) {
      float4 pv  = *(const float4*)&As[s][i0];
      float4 pvv = *(const float4*)&Vs[s][i0];
      float4 kv  = *(const float4*)&Ks[s][j0];
      float pa[4] = {pv.x, pv.y, pv.z, pv.w};
      float qa[4] = {pvv.x, pvv.y, pvv.z, pvv.w};
      float ka[4] = {kv.x, kv.y, kv.z, kv.w};
#pragma unroll
      for (int i = 0; i < 4; ++i)
#pragma unroll
        for (int j = 0; j < 4; ++j) {
          accM[i][j] = fmaf(pa[i], ka[j], accM[i][j]);
          accB[i][j] = fmaf(qa[i], ka[j], accB[i][j]);
        }
    }
    const size_t base = (size_t)cb * 4096;
#pragma unroll
    for (int i = 0; i < 4; ++i) {
      float m0v = ((i0 + i) == (j0 + 0)) ? 1.f : 0.f;
      float m1v = ((i0 + i) == (j0 + 1)) ? 1.f : 0.f;
      float m2v = ((i0 + i) == (j0 + 2)) ? 1.f : 0.f;
      float m3v = ((i0 + i) == (j0 + 3)) ? 1.f : 0.f;
      *(float4*)&Mg[base + (size_t)(i0 + i) * 64 + j0] =
          make_float4(m0v - accM[i][0], m1v - accM[i][1],
                      m2v - accM[i][2], m3v - accM[i][3]);
      *(float4*)&Bg[base + (size_t)(i0 + i) * 64 + j0] =
          make_float4(accB[i][0], accB[i][1], accB[i][2], accB[i][3]);
    }
    const int fr = t >> 2, fc = (t & 3) << 4;
#pragma unroll
    for (int u = 0; u < 4; ++u)
      *(float4*)&Tg[base + (size_t)fr * 64 + fc + 4 * u] =
          *(const float4*)&Tt[fr][fc + 4 * u];
  }
}

// ---------------------------------------------------------------------------
// Phase 2 (parallel scan over chunks), v3: NGRP=8 groups x GSZ=4 chunks.
// ---------------------------------------------------------------------------
__global__ __launch_bounds__(64, 1) void p2a_kernel(
    const float* __restrict__ Mg, const float* __restrict__ Bg,
    float* __restrict__ Mcum, float* __restrict__ Sall,
    float* __restrict__ BGfin) {
  __shared__ __align__(16) float Srow[2][4 * LD];  // ~2 KB
  const int bid  = blockIdx.x;
  const int g    = bid >> 8;
  const int b    = (bid >> 5) & 7;
  const int w    = bid & 31;
  const int lane = threadIdx.x;
  const int rr   = lane >> 4;
  const int jc   = lane & 15;
  const bool isB = (w >= 16);
  const int n    = ((w & 15) << 2) + rr;

  float4 cs;
  if (isB) cs = make_float4(0.f, 0.f, 0.f, 0.f);
  else
    cs = make_float4((jc * 4 + 0) == n ? 1.f : 0.f,
                     (jc * 4 + 1) == n ? 1.f : 0.f,
                     (jc * 4 + 2) == n ? 1.f : 0.f,
                     (jc * 4 + 3) == n ? 1.f : 0.f);

  for (int l = 0; l < GSZ; ++l) {
    const int c   = g * GSZ + l;
    const int cur = l & 1;
    const size_t cbase = ((size_t)c * BB + b) * 4096;
    if (isB) *(float4*)&Sall[cbase + (size_t)n * 64 + jc * 4] = cs;
    else if (l > 0) *(float4*)&Mcum[cbase + (size_t)n * 64 + jc * 4] = cs;
    *(float4*)&Srow[cur][rr * LD + jc * 4] = cs;
    float4 bv = make_float4(0.f, 0.f, 0.f, 0.f);
    if (isB) bv = *(const float4*)&Bg[cbase + (size_t)n * 64 + jc * 4];

    const float* Mrow = Mg + cbase + jc * 4;
    float4 acc = make_float4(0.f, 0.f, 0.f, 0.f);
#pragma unroll
    for (int u = 0; u < 16; ++u) {
      float4 sv = *(const float4*)&Srow[cur][rr * LD + u * 4];
      float4 m0 = *(const float4*)&Mrow[(4 * u + 0) * 64];
      float4 m1 = *(const float4*)&Mrow[(4 * u + 1) * 64];
      float4 m2 = *(const float4*)&Mrow[(4 * u + 2) * 64];
      float4 m3 = *(const float4*)&Mrow[(4 * u + 3) * 64];
      acc.x = fmaf(sv.x, m0.x, acc.x); acc.y = fmaf(sv.x, m0.y, acc.y);
      acc.z = fmaf(sv.x, m0.z, acc.z); acc.w = fmaf(sv.x, m0.w, acc.w);
      acc.x = fmaf(sv.y, m1.x, acc.x); acc.y = fmaf(sv.y, m1.y, acc.y);
      acc.z = fmaf(sv.y, m1.z, acc.z); acc.w = fmaf(sv.y, m1.w, acc.w);
      acc.x = fmaf(sv.z, m2.x, acc.x); acc.y = fmaf(sv.z, m2.y, acc.y);
      acc.z = fmaf(sv.z, m2.z, acc.z); acc.w = fmaf(sv.z, m2.w, acc.w);
      acc.x = fmaf(sv.w, m3.x, acc.x); acc.y = fmaf(sv.w, m3.y, acc.y);
      acc.z = fmaf(sv.w, m3.z, acc.z); acc.w = fmaf(sv.w, m3.w, acc.w);
    }
    cs = make_float4(acc.x + bv.x, acc.y + bv.y, acc.z + bv.z, acc.w + bv.w);
  }
  if (isB)
    *(float4*)&BGfin[((size_t)g * BB + b) * 4096 + (size_t)n * 64 + jc * 4] = cs;
  else
    *(float4*)&Mcum[((size_t)(g * GSZ) * BB + b) * 4096 + (size_t)n * 64 + jc * 4] = cs;
}

__global__ __launch_bounds__(64, 1) void p2b_kernel(
    const float* __restrict__ Mcum, const float* __restrict__ BGfin,
    float* __restrict__ Sall) {
  __shared__ __align__(16) float Srow[2][4 * LD];
  const int bid  = blockIdx.x;
  const int b    = bid >> 4;
  const int w    = bid & 15;
  const int lane = threadIdx.x;
  const int rr   = lane >> 4;
  const int jc   = lane & 15;
  const int n    = w * 4 + rr;

  float4 cs = make_float4(0.f, 0.f, 0.f, 0.f);

  for (int g2 = 0; g2 < NGRP - 1; ++g2) {
    const int cur = g2 & 1;
    *(float4*)&Srow[cur][rr * LD + jc * 4] = cs;
    float4 bv = *(const float4*)&BGfin[((size_t)g2 * BB + b) * 4096 +
                                       (size_t)n * 64 + jc * 4];
    const float* Mrow =
        Mcum + ((size_t)(g2 * GSZ) * BB + b) * 4096 + jc * 4;
    float4 acc = make_float4(0.f, 0.f, 0.f, 0.f);
#pragma unroll
    for (int u = 0; u < 16; ++u) {
      float4 sv = *(const float4*)&Srow[cur][rr * LD + u * 4];
      float4 m0 = *(const float4*)&Mrow[(4 * u + 0) * 64];
      float4 m1 = *(const float4*)&Mrow[(4 * u + 1) * 64];
      float4 m2 = *(const float4*)&Mrow[(4 * u + 2) * 64];
      float4 m3 = *(const float4*)&Mrow[(4 * u + 3) * 64];
      acc.x = fmaf(sv.x, m0.x, acc.x); acc.y = fmaf(sv.x, m0.y, acc.y);
      acc.z = fmaf(sv.x, m0.z, acc.z); acc.w = fmaf(sv.x, m0.w, acc.w);
      acc.x = fmaf(sv.y, m1.x, acc.x); acc.y = fmaf(sv.y, m1.y, acc.y);
      acc.z = fmaf(sv.y, m1.z, acc.z); acc.w = fmaf(sv.y, m1.w, acc.w);
      acc.x = fmaf(sv.z, m2.x, acc.x); acc.y = fmaf(sv.z, m2.y, acc.y);
      acc.z = fmaf(sv.z, m2.z, acc.z); acc.w = fmaf(sv.z, m2.w, acc.w);
      acc.x = fmaf(sv.w, m3.x, acc.x); acc.y = fmaf(sv.w, m3.y, acc.y);
      acc.z = fmaf(sv.w, m3.z, acc.z); acc.w = fmaf(sv.w, m3.w, acc.w);
    }
    cs = make_float4(acc.x + bv.x, acc.y + bv.y, acc.z + bv.z, acc.w + bv.w);
    *(float4*)&Sall[((size_t)((g2 + 1) * GSZ) * BB + b) * 4096 +
                    (size_t)n * 64 + jc * 4] = cs;
  }
}

__global__ __launch_bounds__(256) void p2c_kernel(
    const float* __restrict__ Mcum, float* __restrict__ Sall) {
  __shared__ __align__(16) float SgT[64][LD];
  __shared__ __align__(16) float Mc[64][LD];
  const int idx = blockIdx.x;
  const int b   = idx & 7;
  const int q   = idx >> 3;
  const int g   = 1 + q / (GSZ - 1);
  const int l   = 1 + q % (GSZ - 1);
  const int c   = g * GSZ + l;
  const int t   = threadIdx.x;
  const size_t cbase = ((size_t)c * BB + b) * 4096;
  const size_t gbase = ((size_t)(g * GSZ) * BB + b) * 4096;
  {
    const int tau = t & 63, c0 = (t >> 6) << 4;
    const float* sgp = Sall + gbase + (size_t)tau * 64 + c0;
    const float* mcp = Mcum + cbase + (size_t)tau * 64 + c0;
#pragma unroll
    for (int u = 0; u < 4; ++u) {
      float4 sv = *(const float4*)&sgp[4 * u];
      SgT[c0 + 4 * u + 0][tau] = sv.x;
      SgT[c0 + 4 * u + 1][tau] = sv.y;
      SgT[c0 + 4 * u + 2][tau] = sv.z;
      SgT[c0 + 4 * u + 3][tau] = sv.w;
      *(float4*)&Mc[tau][c0 + 4 * u] = *(const float4*)&mcp[4 * u];
    }
  }
  __syncthreads();
  const int i0 = (t >> 4) << 2;
  const int j0 = (t & 15) << 2;
  float acc[4][4];
#pragma unroll
  for (int i = 0; i < 4; ++i)
#pragma unroll
    for (int j = 0; j < 4; ++j) acc[i][j] = 0.f;
  for (int m = 0; m < 64; ++m) {
    float4 tv = *(const float4*)&SgT[m][i0];
    float4 kv = *(const float4*)&Mc[m][j0];
    float ta[4] = {tv.x, tv.y, tv.z, tv.w};
    float ka[4] = {kv.x, kv.y, kv.z, kv.w};
#pragma unroll
    for (int i = 0; i < 4; ++i)
#pragma unroll
      for (int j = 0; j < 4; ++j) acc[i][j] = fmaf(ta[i], ka[j], acc[i][j]);
  }
  float* dst = Sall + cbase;
#pragma unroll
  for (int i = 0; i < 4; ++i) {
    float4 d = *(float4*)&dst[(size_t)(i0 + i) * 64 + j0];
    d.x += acc[i][0]; d.y += acc[i][1];
    d.z += acc[i][2]; d.w += acc[i][3];
    *(float4*)&dst[(size_t)(i0 + i) * 64 + j0] = d;
  }
}

// ---------------------------------------------------------------------------
// Phase 3: Gt = (Q K^T)^T ; W = V - K S0^T ; U = T W ;
//   Y = Q S0^T + tril(G) U ; y = tanh(Y) * sigmoid(Z)  -> ys (f16)
// K normalized on load; Gt gather remapped (conflict-free).
// ---------------------------------------------------------------------------
__global__ __launch_bounds__(256) void phase3_kernel(
    const float* __restrict__ kvqz, const float* __restrict__ Tg,
    const float* __restrict__ Sall, _Float16* __restrict__ ys) {
  __shared__ __align__(16) float Ks[64][LD];   // K, then W, then U
  __shared__ __align__(16) float Qs[64][LD];
  __shared__ __align__(16) float S0s[64][LD];
  __shared__ __align__(16) float Gts[64][LD];
  const int cb = blockIdx.x;
  const int c  = cb >> 3, b = cb & 7;
  const int t  = threadIdx.x;
  const size_t base = (size_t)cb * 4096;

  {
    const int tau = t >> 2, m0q = (t & 3) << 4;
    const float* src = kvqz + (size_t)((c * 64 + tau) * BB + b) * 256;
    float4 kv[4];
    float ss = 0.f;
#pragma unroll
    for (int u = 0; u < 4; ++u) {
      kv[u] = *(const float4*)&src[m0q + 4 * u];
      ss += dot4(kv[u], kv[u]);
      *(float4*)&Qs[tau][m0q + 4 * u]  = *(const float4*)&src[128 + m0q + 4 * u];
      *(float4*)&S0s[tau][m0q + 4 * u] = *(const float4*)&Sall[base + (size_t)tau * 64 + m0q + 4 * u];
    }
    ss += __shfl_xor(ss, 1);
    ss += __shfl_xor(ss, 2);
    const float sc = 1.f / (sqrtf(ss) + 1e-6f);
#pragma unroll
    for (int u = 0; u < 4; ++u) {
      kv[u].x *= sc; kv[u].y *= sc; kv[u].z *= sc; kv[u].w *= sc;
      *(float4*)&Ks[tau][m0q + 4 * u] = kv[u];
    }
  }
  __syncthreads();

  const int i0 = (t >> 4) << 2;
  const int j0 = (t & 15) << 2;
  const int jc = t & 15;

  {  // Gt[s][tq] = sum_m K[s][m] Q[tq][m]  (tq = jc+16*jj remap)
    float acc[4][4];
#pragma unroll
    for (int i = 0; i < 4; ++i)
#pragma unroll
      for (int j = 0; j < 4; ++j) acc[i][j] = 0.f;
#pragma unroll 2
    for (int m4 = 0; m4 < 64; m4 += 4) {
      float4 kr[4], qr[4];
#pragma unroll
      for (int i = 0; i < 4; ++i) kr[i] = *(const float4*)&Ks[i0 + i][m4];
#pragma unroll
      for (int j = 0; j < 4; ++j) qr[j] = *(const float4*)&Qs[jc + 16 * j][m4];
#pragma unroll
      for (int i = 0; i < 4; ++i)
#pragma unroll
        for (int j = 0; j < 4; ++j) acc[i][j] += dot4(kr[i], qr[j]);
    }
#pragma unroll
    for (int i = 0; i < 4; ++i)
#pragma unroll
      for (int j = 0; j < 4; ++j) Gts[i0 + i][jc + 16 * j] = acc[i][j];
  }

  {  // W[tau][n] = V[tau][n] - sum_m K[tau][m] S0[n][m]  -> Ks slot
    float acc[4][4];
#pragma unroll
    for (int i = 0; i < 4; ++i) {
      const float* vrow = kvqz + (size_t)((c * 64 + i0 + i) * BB + b) * 256 + 64;
      float4 vv = *(const float4*)&vrow[j0];
      acc[i][0] = vv.x; acc[i][1] = vv.y; acc[i][2] = vv.z; acc[i][3] = vv.w;
    }
#pragma unroll 2
    for (int m4 = 0; m4 < 64; m4 += 4) {
      float4 kr[4], sr[4];
#pragma unroll
      for (int i = 0; i < 4; ++i) kr[i] = *(const float4*)&Ks[i0 + i][m4];
#pragma unroll
      for (int j = 0; j < 4; ++j) sr[j] = *(const float4*)&S0s[j0 + j][m4];
#pragma unroll
      for (int i = 0; i < 4; ++i)
#pragma unroll
        for (int j = 0; j < 4; ++j) acc[i][j] -= dot4(kr[i], sr[j]);
    }
    __syncthreads();   // all reads of Ks (stages 1+2) complete
#pragma unroll
    for (int i = 0; i < 4; ++i)
      *(float4*)&Ks[i0 + i][j0] =
          make_float4(acc[i][0], acc[i][1], acc[i][2], acc[i][3]);
  }
  __syncthreads();

  float4 zv[4];
  {  // U[tq][n] = sum_s Tt[s][tq] W[s][n]  (Tt from global; W in Ks slot)
#pragma unroll
    for (int i = 0; i < 4; ++i) {
      const float* zrow = kvqz + (size_t)((c * 64 + i0 + i) * BB + b) * 256 + 192;
      zv[i] = *(const float4*)&zrow[j0];
    }
    float acc[4][4];
#pragma unroll
    for (int i = 0; i < 4; ++i)
#pragma unroll
      for (int j = 0; j < 4; ++j) acc[i][j] = 0.f;
    const float* Tp = Tg + base + i0;
#pragma unroll 4
    for (int s = 0; s < 64; ++s) {
      float4 tv = *(const float4*)&Tp[(size_t)s * 64];   // broadcast per quad
      float4 wv = *(const float4*)&Ks[s][j0];
      float ta[4] = {tv.x, tv.y, tv.z, tv.w};
      float wa[4] = {wv.x, wv.y, wv.z, wv.w};
#pragma unroll
      for (int i = 0; i < 4; ++i)
#pragma unroll
        for (int j = 0; j < 4; ++j) acc[i][j] = fmaf(ta[i], wa[j], acc[i][j]);
    }
    __syncthreads();   // all reads of W complete before overwrite
#pragma unroll
    for (int i = 0; i < 4; ++i)
      *(float4*)&Ks[i0 + i][j0] =
          make_float4(acc[i][0], acc[i][1], acc[i][2], acc[i][3]);
  }
  __syncthreads();

  {  // Y = Q S0^T + tril(G) U ; out (f16)   (U in Ks slot)
    float acc[4][4];
#pragma unroll
    for (int i = 0; i < 4; ++i)
#pragma unroll
      for (int j = 0; j < 4; ++j) acc[i][j] = 0.f;
#pragma unroll 2
    for (int m4 = 0; m4 < 64; m4 += 4) {
      float4 qr[4], sr[4];
#pragma unroll
      for (int i = 0; i < 4; ++i) qr[i] = *(const float4*)&Qs[i0 + i][m4];
#pragma unroll
      for (int j = 0; j < 4; ++j) sr[j] = *(const float4*)&S0s[j0 + j][m4];
#pragma unroll
      for (int i = 0; i < 4; ++i)
#pragma unroll
        for (int j = 0; j < 4; ++j) acc[i][j] += dot4(qr[i], sr[j]);
    }
#pragma unroll 4
    for (int s = 0; s < 64; ++s) {
      float4 gv = *(const float4*)&Gts[s][i0];
      float4 uv = *(const float4*)&Ks[s][j0];
      float ga[4] = {gv.x, gv.y, gv.z, gv.w};
      float ua[4] = {uv.x, uv.y, uv.z, uv.w};
#pragma unroll
      for (int i = 0; i < 4; ++i) {
        float gi = (s <= i0 + i) ? ga[i] : 0.f;
#pragma unroll
        for (int j = 0; j < 4; ++j) acc[i][j] = fmaf(gi, ua[j], acc[i][j]);
      }
    }
#pragma unroll
    for (int i = 0; i < 4; ++i) {
      float za[4] = {zv[i].x, zv[i].y, zv[i].z, zv[i].w};
      _Float16 oh[4];
#pragma unroll
      for (int j = 0; j < 4; ++j) {
        float e2 = __expf(2.f * acc[i][j]);
        float th = 1.f - 2.f / (e2 + 1.f);
        float sg = 1.f / (1.f + __expf(-za[j]));
        oh[j] = (_Float16)(th * sg);
      }
      half4h o4 = {oh[0], oh[1], oh[2], oh[3]};
      *(half4h*)&ys[(size_t)((c * 64 + i0 + i) * BB + b) * 64 + j0] = o4;
    }
  }
}

// ---------------------------------------------------------------------------
extern "C" void kernel_launch(void* const* d_in, const int* in_sizes, int n_in,
                              void* d_out, int out_size, void* d_ws, size_t ws_size,
                              hipStream_t stream) {
  const float* x    = (const float*)d_in[0];
  const float* Win  = (const float*)d_in[1];
  const float* Wk   = (const float*)d_in[2];
  const float* Wv   = (const float*)d_in[3];
  const float* Wq   = (const float*)d_in[4];
  const float* Wz   = (const float*)d_in[5];
  const float* Wout = (const float*)d_in[6];
  float* out = (float*)d_out;

  char* ws = (char*)d_ws;
  // Liveness-checked layout (fp32 unless noted):
  //   [0,1M):    Wfh (f16, [0,512K); fuse_reduce4 -> kvqz GEMM), then
  //              BGfin (1M; p2a -> p2b), then Woh (f16, [0,128K); cvt AFTER
  //              p2b/p2c -> final GEMM).  Strictly sequential.
  //   [1M,17M):  kvqz (kvqz GEMM -> phase3).
  //   [17M,21M): Mcum (p2a -> p2c; l=0 slots carry MGfin for p2b);
  //              ysh (f16) [17M,19M) (phase3 -> final GEMM, after Mcum dead).
  //   [21M,37M): fuse scratch (Wgh f16 [21M,22M), WinTh f16 [22M,26M),
  //              Pg4 [26M,30M)) -- all dead before cvt_x writes xh; then
  //              xh (f16; [21M,53M) if ws>=53MB else 16MB halves); then
  //              Tg/Mg/Bg/Sall (phase1 -> phase3).
  _Float16* Wfh  = (_Float16*)(ws);
  float* BGfin   = (float*)(ws);              // written by p2a (Wfh dead)
  _Float16* Woh  = (_Float16*)(ws);           // written after p2b (BGfin dead)
  float* kvqz    = (float*)(ws + (1u  << 20));
  _Float16* ysh  = (_Float16*)(ws + (17u << 20));
  float* Mcum    = (float*)(ws + (17u << 20));
  _Float16* Wgh  = (_Float16*)(ws + (21u << 20));
  _Float16* WinTh= (_Float16*)(ws + (22u << 20));
  float* Pg4     = (float*)(ws + (26u << 20));
  float* Tg      = (float*)(ws + (21u << 20));
  float* Mg      = (float*)(ws + (25u << 20));
  float* Bg      = (float*)(ws + (29u << 20));
  float* Sall    = (float*)(ws + (33u << 20));
  _Float16* xh   = (_Float16*)(ws + (21u << 20));

  // fuse path (MFMA): Wf = Wg[256][2048] x Win[2048][1024], f16 inputs.
  pack_wg_kernel<<<256, 256, 0, stream>>>(Wk, Wv, Wq, Wz, Wgh);
  transpose_win_kernel<<<dim3(DIM_ / 64, DI_ / 64), 256, 0, stream>>>(Win, WinTh);
  gemm_h16_splitk<<<dim3(DIM_ / 64, 256 / 64, FKS), 256, 0, stream>>>(
      Wgh, WinTh, Pg4, 256, DIM_, DI_, DI_ / FKS);
  fuse_reduce4_kernel<<<(256 * DIM_ / 4) / 256, 256, 0, stream>>>(Pg4, Wfh);

  if (ws_size >= (53ull << 20)) {
    cvt_f16_kernel<<<2048, 256, 0, stream>>>(x, xh, (long)MR_ * DIM_ / 8);
    gemm_h16<<<dim3(256 / 64, MR_ / 64), 256, 0, stream>>>(xh, Wfh, kvqz, MR_, 256, DIM_);
  } else {
    const long half_rows = MR_ / 2;
    for (int h = 0; h < 2; ++h) {
      const float* xs = x + (size_t)h * half_rows * DIM_;
      float* cs = kvqz + (size_t)h * half_rows * 256;
      cvt_f16_kernel<<<2048, 256, 0, stream>>>(xs, xh, half_rows * DIM_ / 8);
      gemm_h16<<<dim3(256 / 64, (int)(half_rows / 64)), 256, 0, stream>>>(
          xh, Wfh, cs, (int)half_rows, 256, DIM_);
    }
  }

  phase1_kernel<<<NCH * BB, 256, 0, stream>>>(kvqz, Tg, Mg, Bg);
  p2a_kernel<<<NGRP * BB * 32, 64, 0, stream>>>(Mg, Bg, Mcum, Sall, BGfin);
  p2b_kernel<<<16 * BB, 64, 0, stream>>>(Mcum, BGfin, Sall);
  p2c_kernel<<<(NGRP - 1) * (GSZ - 1) * BB, 256, 0, stream>>>(Mcum, Sall);
  // Wout -> f16 AFTER p2b: [0,128K) is free (Wfh and BGfin both dead).
  cvt_f16_kernel<<<32, 256, 0, stream>>>(Wout, Woh, (long)(DIM_ * NS_ / 8));
  phase3_kernel<<<NCH * BB, 256, 0, stream>>>(kvqz, Tg, Sall, ysh);
  gemm_h16<<<dim3(DIM_ / 64, MR_ / 64), 256, 0, stream>>>(ysh, Woh, out, MR_, DIM_, NS_);
}

// Round 11
// 264.795 us; speedup vs baseline: 1.0752x; 1.0168x over previous
//
#include <hip/hip_runtime.h>
#include <math.h>

#define TT   2048
#define BB   8
#define DIM_ 1024
#define DI_  2048
#define NS_  64
#define MR_  (TT * BB)   // 16384 rows (t-major, b-minor)
#define NCH  32          // chunks of 64 steps
#define LD   68          // padded LDS leading dim (16B-aligned rows)
#define NGRP 8           // scan groups
#define GSZ  4           // chunks per group (NGRP*GSZ == NCH)
#define LDH2 40          // padded f16 LDS stride for gemm_h16 (80 B rows)
#define FKS  4           // fuse GEMM split-K factor

typedef _Float16 half8 __attribute__((ext_vector_type(8)));
typedef _Float16 half4h __attribute__((ext_vector_type(4)));
typedef float floatx4 __attribute__((ext_vector_type(4)));

__device__ __forceinline__ float dot4(float4 a, float4 b) {
  return a.x * b.x + a.y * b.y + a.z * b.z + a.w * b.w;
}

__device__ __forceinline__ half8 cvt8(float4 lo, float4 hi) {
  half8 h = {(_Float16)lo.x, (_Float16)lo.y, (_Float16)lo.z, (_Float16)lo.w,
             (_Float16)hi.x, (_Float16)hi.y, (_Float16)hi.z, (_Float16)hi.w};
  return h;
}

// ---------------------------------------------------------------------------
// fp32 -> f16 elementwise convert (n8 groups of 8 elems), grid-stride.
// ---------------------------------------------------------------------------
__global__ __launch_bounds__(256) void cvt_f16_kernel(
    const float* __restrict__ in, _Float16* __restrict__ out, long n8) {
  long i = (long)blockIdx.x * 256 + threadIdx.x;
  const long stride = (long)gridDim.x * 256;
  for (; i < n8; i += stride) {
    const float4 lo = *(const float4*)&in[i * 8];
    const float4 hi = *(const float4*)&in[i * 8 + 4];
    *(half8*)&out[i * 8] = cvt8(lo, hi);
  }
}

// ---------------------------------------------------------------------------
// Merged fuse-path prep (one launch instead of three):
//   blocks [0,512):   Win[2048][1024] fp32 -> WinTh[1024][2048] f16 (transpose)
//   blocks [512,768): pack Wk/Wv/Wq/Wz -> Wgh[256][2048] f16
//   blocks [768,800): Wout -> Woh f16 (skipped when woh == nullptr)
// ---------------------------------------------------------------------------
__global__ __launch_bounds__(256) void fuse_prep_kernel(
    const float* __restrict__ Wk, const float* __restrict__ Wv,
    const float* __restrict__ Wq, const float* __restrict__ Wz,
    const float* __restrict__ Win, const float* __restrict__ Wout,
    _Float16* __restrict__ Wgh, _Float16* __restrict__ WinTh,
    _Float16* __restrict__ woh) {
  const int bb = blockIdx.x;
  const int t  = threadIdx.x;
  if (bb < 512) {  // transpose+convert Win tile
    __shared__ float T[64][65];
    const int c0 = (bb & 15) * 64;   // Win col base
    const int r0 = (bb >> 4) * 64;   // Win row base
    {
      const int tr = t >> 2, tc = (t & 3) * 16;
#pragma unroll
      for (int u = 0; u < 4; ++u) {
        float4 v = *(const float4*)&Win[(size_t)(r0 + tr) * DIM_ + c0 + tc + 4 * u];
        T[tr][tc + 4 * u + 0] = v.x;
        T[tr][tc + 4 * u + 1] = v.y;
        T[tr][tc + 4 * u + 2] = v.z;
        T[tr][tc + 4 * u + 3] = v.w;
      }
    }
    __syncthreads();
    {
      const int oc = t >> 2;
      const int orr = (t & 3) * 16;
      _Float16 h[16];
#pragma unroll
      for (int u = 0; u < 16; ++u) h[u] = (_Float16)T[orr + u][oc];
      _Float16* dst = WinTh + (size_t)(c0 + oc) * DI_ + r0 + orr;
      *(half8*)&dst[0] = *(half8*)&h[0];
      *(half8*)&dst[8] = *(half8*)&h[8];
    }
  } else if (bb < 768) {  // pack Wg
    const float* Wg[4] = {Wk, Wv, Wq, Wz};
    const long g = (long)(bb - 512) * 256 + t;  // [0, 65536)
    const int row = (int)(g >> 8);
    const int k   = (int)((g & 255) << 3);
    const float* src = Wg[row >> 6] + (size_t)(row & 63) * DI_ + k;
    const float4 lo = *(const float4*)&src[0];
    const float4 hi = *(const float4*)&src[4];
    *(half8*)&Wgh[(size_t)row * DI_ + k] = cvt8(lo, hi);
  } else if (woh != nullptr) {  // Wout cvt (early path)
    const long i = (long)(bb - 768) * 256 + t;  // [0, 8192)
    const float4 lo = *(const float4*)&Wout[i * 8];
    const float4 hi = *(const float4*)&Wout[i * 8 + 4];
    *(half8*)&woh[i * 8] = cvt8(lo, hi);
  }
}

// ---------------------------------------------------------------------------
// f16 MFMA GEMM: C[M,N] = A[M,K] * B[N,K]^T, A/B already f16 row-major.
// BM=64 x BN=64 tile, BK=32, 4 waves in 2x2 (wave tile 32x32, 2x2 MFMA).
// ---------------------------------------------------------------------------
__global__ __launch_bounds__(256) void gemm_h16(
    const _Float16* __restrict__ A, const _Float16* __restrict__ B,
    float* __restrict__ C, int M, int N, int K) {
  __shared__ __align__(16) _Float16 Ah[2][64 * LDH2];  // 2 x 5 KB
  __shared__ __align__(16) _Float16 Bh[2][64 * LDH2];  // 2 x 5 KB
  const int tid  = threadIdx.x;
  const int m0   = blockIdx.y * 64;
  const int n0   = blockIdx.x * 64;
  const int wave = tid >> 6, lane = tid & 63;
  const int wm   = (wave >> 1) * 32;   // wave row base (0/32)
  const int wn   = (wave & 1) * 32;    // wave col base (0/32)
  const int quad = lane >> 4, l16 = lane & 15;
  const int srow = tid >> 2;           // stage row 0..63
  const int scol = (tid & 3) * 8;      // stage k-offset (f16 elems)

  const _Float16* Ap = A + (size_t)(m0 + srow) * K + scol;
  const _Float16* Bp = B + (size_t)(n0 + srow) * K + scol;

  floatx4 acc[2][2];
#pragma unroll
  for (int i = 0; i < 2; ++i)
#pragma unroll
    for (int j = 0; j < 2; ++j) acc[i][j] = (floatx4)0.f;

  half8 ha, hb;
  ha = *(const half8*)(Ap);
  hb = *(const half8*)(Bp);
  *(half8*)&Ah[0][srow * LDH2 + scol] = ha;
  *(half8*)&Bh[0][srow * LDH2 + scol] = hb;
  __syncthreads();

  const int NK = K >> 5;
  for (int kt = 0; kt < NK; ++kt) {
    const int cur = kt & 1;
    if (kt + 1 < NK) {
      ha = *(const half8*)(Ap + (kt + 1) * 32);
      hb = *(const half8*)(Bp + (kt + 1) * 32);
    }
    half8 af[2], bf[2];
#pragma unroll
    for (int mt = 0; mt < 2; ++mt)
      af[mt] = *(const half8*)&Ah[cur][(wm + mt * 16 + l16) * LDH2 + quad * 8];
#pragma unroll
    for (int nt = 0; nt < 2; ++nt)
      bf[nt] = *(const half8*)&Bh[cur][(wn + nt * 16 + l16) * LDH2 + quad * 8];
#pragma unroll
    for (int mt = 0; mt < 2; ++mt)
#pragma unroll
      for (int nt = 0; nt < 2; ++nt)
        acc[mt][nt] = __builtin_amdgcn_mfma_f32_16x16x32_f16(
            af[mt], bf[nt], acc[mt][nt], 0, 0, 0);
    if (kt + 1 < NK) {
      const int nxt = cur ^ 1;
      *(half8*)&Ah[nxt][srow * LDH2 + scol] = ha;
      *(half8*)&Bh[nxt][srow * LDH2 + scol] = hb;
    }
    __syncthreads();
  }

#pragma unroll
  for (int mt = 0; mt < 2; ++mt) {
#pragma unroll
    for (int i = 0; i < 4; ++i) {
      const size_t r = (size_t)(m0 + wm + mt * 16 + quad * 4 + i) * N;
#pragma unroll
      for (int nt = 0; nt < 2; ++nt)
        C[r + n0 + wn + nt * 16 + l16] = acc[mt][nt][i];
    }
  }
}

// Split-K variant: blockIdx.z selects a K-chunk; partial to Cp[z][M][N].
__global__ __launch_bounds__(256) void gemm_h16_splitk(
    const _Float16* __restrict__ A, const _Float16* __restrict__ B,
    float* __restrict__ Cp, int M, int N, int K, int kchunk) {
  __shared__ __align__(16) _Float16 Ah[2][64 * LDH2];
  __shared__ __align__(16) _Float16 Bh[2][64 * LDH2];
  const int tid  = threadIdx.x;
  const int m0   = blockIdx.y * 64;
  const int n0   = blockIdx.x * 64;
  const int kb   = blockIdx.z * kchunk;
  const int wave = tid >> 6, lane = tid & 63;
  const int wm   = (wave >> 1) * 32;
  const int wn   = (wave & 1) * 32;
  const int quad = lane >> 4, l16 = lane & 15;
  const int srow = tid >> 2;
  const int scol = (tid & 3) * 8;

  const _Float16* Ap = A + (size_t)(m0 + srow) * K + kb + scol;
  const _Float16* Bp = B + (size_t)(n0 + srow) * K + kb + scol;
  float* C = Cp + (size_t)blockIdx.z * M * N;

  floatx4 acc[2][2];
#pragma unroll
  for (int i = 0; i < 2; ++i)
#pragma unroll
    for (int j = 0; j < 2; ++j) acc[i][j] = (floatx4)0.f;

  half8 ha, hb;
  ha = *(const half8*)(Ap);
  hb = *(const half8*)(Bp);
  *(half8*)&Ah[0][srow * LDH2 + scol] = ha;
  *(half8*)&Bh[0][srow * LDH2 + scol] = hb;
  __syncthreads();

  const int NK = kchunk >> 5;
  for (int kt = 0; kt < NK; ++kt) {
    const int cur = kt & 1;
    if (kt + 1 < NK) {
      ha = *(const half8*)(Ap + (kt + 1) * 32);
      hb = *(const half8*)(Bp + (kt + 1) * 32);
    }
    half8 af[2], bf[2];
#pragma unroll
    for (int mt = 0; mt < 2; ++mt)
      af[mt] = *(const half8*)&Ah[cur][(wm + mt * 16 + l16) * LDH2 + quad * 8];
#pragma unroll
    for (int nt = 0; nt < 2; ++nt)
      bf[nt] = *(const half8*)&Bh[cur][(wn + nt * 16 + l16) * LDH2 + quad * 8];
#pragma unroll
    for (int mt = 0; mt < 2; ++mt)
#pragma unroll
      for (int nt = 0; nt < 2; ++nt)
        acc[mt][nt] = __builtin_amdgcn_mfma_f32_16x16x32_f16(
            af[mt], bf[nt], acc[mt][nt], 0, 0, 0);
    if (kt + 1 < NK) {
      const int nxt = cur ^ 1;
      *(half8*)&Ah[nxt][srow * LDH2 + scol] = ha;
      *(half8*)&Bh[nxt][srow * LDH2 + scol] = hb;
    }
    __syncthreads();
  }

#pragma unroll
  for (int mt = 0; mt < 2; ++mt) {
#pragma unroll
    for (int i = 0; i < 4; ++i) {
      const size_t r = (size_t)(m0 + wm + mt * 16 + quad * 4 + i) * N;
#pragma unroll
      for (int nt = 0; nt < 2; ++nt)
        C[r + n0 + wn + nt * 16 + l16] = acc[mt][nt][i];
    }
  }
}

// Wfh[i] = (f16) sum_{z<FKS} Pg4[z][i]
__global__ __launch_bounds__(256) void fuse_reduce4_kernel(
    const float* __restrict__ Pg4, _Float16* __restrict__ Wfh) {
  const size_t i = ((size_t)blockIdx.x * 256 + threadIdx.x) << 2;
  float4 s = *(const float4*)&Pg4[i];
#pragma unroll
  for (int z = 1; z < FKS; ++z) {
    float4 p = *(const float4*)&Pg4[(size_t)z * (256 * DIM_) + i];
    s.x += p.x; s.y += p.y; s.z += p.z; s.w += p.w;
  }
  half4h h = {(_Float16)s.x, (_Float16)s.y, (_Float16)s.z, (_Float16)s.w};
  *(half4h*)&Wfh[i] = h;
}

// ---------------------------------------------------------------------------
// Phase 1: per chunk-batch:  A = K K^T ; Tt = inv(I+stril(A)) (transposed);
// P = T K ; Pv = T V ; M = I - P^T K ; B = Pv^T K.  Store Tt, M, B.
// K rows unit-normalized on load; A=KK^T gather conflict-free remap.
// ---------------------------------------------------------------------------
__global__ __launch_bounds__(256) void phase1_kernel(
    const float* __restrict__ kvqz, float* __restrict__ Tg,
    float* __restrict__ Mg, float* __restrict__ Bg) {
  __shared__ __align__(16) float Ks[64][LD];
  __shared__ __align__(16) float Vs[64][LD];   // V, then Pv
  __shared__ __align__(16) float As[64][LD];   // A=KK^T, then P
  __shared__ __align__(16) float Tt[64][LD];
  const int cb = blockIdx.x;
  const int c  = cb >> 3, b = cb & 7;
  const int t  = threadIdx.x;

  {
    const int tau = t >> 2, m0q = (t & 3) << 4;
    const float* src = kvqz + (size_t)((c * 64 + tau) * BB + b) * 256;
    float4 kv[4];
    float ss = 0.f;
#pragma unroll
    for (int u = 0; u < 4; ++u) {
      kv[u] = *(const float4*)&src[m0q + 4 * u];
      ss += dot4(kv[u], kv[u]);
      *(float4*)&Vs[tau][m0q + 4 * u] = *(const float4*)&src[64 + m0q + 4 * u];
    }
    ss += __shfl_xor(ss, 1);
    ss += __shfl_xor(ss, 2);
    const float sc = 1.f / (sqrtf(ss) + 1e-6f);
#pragma unroll
    for (int u = 0; u < 4; ++u) {
      kv[u].x *= sc; kv[u].y *= sc; kv[u].z *= sc; kv[u].w *= sc;
      *(float4*)&Ks[tau][m0q + 4 * u] = kv[u];
    }
  }
  __syncthreads();

  const int i0 = (t >> 4) << 2;
  const int j0 = (t & 15) << 2;
  const int jc = t & 15;

  {  // A = K K^T  (cols jc+16*jj: consecutive-row gather, 2-way = free)
    float acc[4][4];
#pragma unroll
    for (int i = 0; i < 4; ++i)
#pragma unroll
      for (int j = 0; j < 4; ++j) acc[i][j] = 0.f;
#pragma unroll 2
    for (int m4 = 0; m4 < 64; m4 += 4) {
      float4 ar[4], br[4];
#pragma unroll
      for (int i = 0; i < 4; ++i) ar[i] = *(const float4*)&Ks[i0 + i][m4];
#pragma unroll
      for (int j = 0; j < 4; ++j) br[j] = *(const float4*)&Ks[jc + 16 * j][m4];
#pragma unroll
      for (int i = 0; i < 4; ++i)
#pragma unroll
        for (int j = 0; j < 4; ++j) acc[i][j] += dot4(ar[i], br[j]);
    }
#pragma unroll
    for (int i = 0; i < 4; ++i)
#pragma unroll
      for (int j = 0; j < 4; ++j) As[i0 + i][jc + 16 * j] = acc[i][j];
  }
  __syncthreads();

  if (t < 64) {  // register forward substitution (fully unrolled, tt in VGPRs)
    const int j = t;
    float tt[64];
    tt[0] = (j == 0) ? 1.f : 0.f;
#pragma unroll
    for (int i = 1; i < 64; ++i) {
      float p0 = 0.f, p1 = 0.f, p2 = 0.f, p3 = 0.f;
      const int nf = i >> 2;
#pragma unroll
      for (int s4 = 0; s4 < nf; ++s4) {
        float4 av = *(const float4*)&As[i][4 * s4];   // broadcast (uniform)
        p0 = fmaf(av.x, tt[4 * s4 + 0], p0);
        p1 = fmaf(av.y, tt[4 * s4 + 1], p1);
        p2 = fmaf(av.z, tt[4 * s4 + 2], p2);
        p3 = fmaf(av.w, tt[4 * s4 + 3], p3);
      }
#pragma unroll
      for (int s = 4 * nf; s < i; ++s) p0 = fmaf(As[i][s], tt[s], p0);
      tt[i] = (i == j) ? 1.f : -((p0 + p1) + (p2 + p3));
    }
#pragma unroll
    for (int u = 0; u < 16; ++u)
      *(float4*)&Tt[j][4 * u] = make_float4(tt[4 * u + 0], tt[4 * u + 1],
                                            tt[4 * u + 2], tt[4 * u + 3]);
  }
  __syncthreads();

  {  // P = T K -> As ; Pv = T V -> Vs (barrier before overwrite)
    float accP[4][4], accV[4][4];
#pragma unroll
    for (int i = 0; i < 4; ++i)
#pragma unroll
      for (int j = 0; j < 4; ++j) { accP[i][j] = 0.f; accV[i][j] = 0.f; }
#pragma unroll 4
    for (int s = 0; s < 64; ++s) {
      float4 tv = *(const float4*)&Tt[s][i0];
      float4 kv = *(const float4*)&Ks[s][j0];
      float4 vv = *(const float4*)&Vs[s][j0];
      float ta[4] = {tv.x, tv.y, tv.z, tv.w};
      float ka[4] = {kv.x, kv.y, kv.z, kv.w};
      float va[4] = {vv.x, vv.y, vv.z, vv.w};
#pragma unroll
      for (int i = 0; i < 4; ++i)
#pragma unroll
        for (int j = 0; j < 4; ++j) {
          accP[i][j] = fmaf(ta[i], ka[j], accP[i][j]);
          accV[i][j] = fmaf(ta[i], va[j], accV[i][j]);
        }
    }
    __syncthreads();
#pragma unroll
    for (int i = 0; i < 4; ++i) {
      *(float4*)&As[i0 + i][j0] =
          make_float4(accP[i][0], accP[i][1], accP[i][2], accP[i][3]);
      *(float4*)&Vs[i0 + i][j0] =
          make_float4(accV[i][0], accV[i][1], accV[i][2], accV[i][3]);
    }
  }
  __syncthreads();

  {  // M = I - P^T K ; B = Pv^T K  -> global   (Pv lives in Vs)
    float accM[4][4], accB[4][4];
#pragma unroll
    for (int i = 0; i < 4; ++i)
#pragma unroll
      for (int j = 0; j < 4; ++j) { accM[i][j] = 0.f; accB[i][j] = 0.f; }
#pragma unroll 4
    for (int s = 0; s < 64; ++s) {
      float4 pv  = *(const float4*)&As[s][i0];
      float4 pvv = *(const float4*)&Vs[s][i0];
      float4 kv  = *(const float4*)&Ks[s][j0];
      float pa[4] = {pv.x, pv.y, pv.z, pv.w};
      float qa[4] = {pvv.x, pvv.y, pvv.z, pvv.w};
      float ka[4] = {kv.x, kv.y, kv.z, kv.w};
#pragma unroll
      for (int i = 0; i < 4; ++i)
#pragma unroll
        for (int j = 0; j < 4; ++j) {
          accM[i][j] = fmaf(pa[i], ka[j], accM[i][j]);
          accB[i][j] = fmaf(qa[i], ka[j], accB[i][j]);
        }
    }
    const size_t base = (size_t)cb * 4096;
#pragma unroll
    for (int i = 0; i < 4; ++i) {
      float m0v = ((i0 + i) == (j0 + 0)) ? 1.f : 0.f;
      float m1v = ((i0 + i) == (j0 + 1)) ? 1.f : 0.f;
      float m2v = ((i0 + i) == (j0 + 2)) ? 1.f : 0.f;
      float m3v = ((i0 + i) == (j0 + 3)) ? 1.f : 0.f;
      *(float4*)&Mg[base + (size_t)(i0 + i) * 64 + j0] =
          make_float4(m0v - accM[i][0], m1v - accM[i][1],
                      m2v - accM[i][2], m3v - accM[i][3]);
      *(float4*)&Bg[base + (size_t)(i0 + i) * 64 + j0] =
          make_float4(accB[i][0], accB[i][1], accB[i][2], accB[i][3]);
    }
    const int fr = t >> 2, fc = (t & 3) << 4;
#pragma unroll
    for (int u = 0; u < 4; ++u)
      *(float4*)&Tg[base + (size_t)fr * 64 + fc + 4 * u] =
          *(const float4*)&Tt[fr][fc + 4 * u];
  }
}

// ---------------------------------------------------------------------------
// Phase 2 (parallel scan over chunks), v3: NGRP=8 groups x GSZ=4 chunks.
// ---------------------------------------------------------------------------
__global__ __launch_bounds__(64, 1) void p2a_kernel(
    const float* __restrict__ Mg, const float* __restrict__ Bg,
    float* __restrict__ Mcum, float* __restrict__ Sall,
    float* __restrict__ BGfin) {
  __shared__ __align__(16) float Srow[2][4 * LD];  // ~2 KB
  const int bid  = blockIdx.x;
  const int g    = bid >> 8;
  const int b    = (bid >> 5) & 7;
  const int w    = bid & 31;
  const int lane = threadIdx.x;
  const int rr   = lane >> 4;
  const int jc   = lane & 15;
  const bool isB = (w >= 16);
  const int n    = ((w & 15) << 2) + rr;

  float4 cs;
  if (isB) cs = make_float4(0.f, 0.f, 0.f, 0.f);
  else
    cs = make_float4((jc * 4 + 0) == n ? 1.f : 0.f,
                     (jc * 4 + 1) == n ? 1.f : 0.f,
                     (jc * 4 + 2) == n ? 1.f : 0.f,
                     (jc * 4 + 3) == n ? 1.f : 0.f);

  for (int l = 0; l < GSZ; ++l) {
    const int c   = g * GSZ + l;
    const int cur = l & 1;
    const size_t cbase = ((size_t)c * BB + b) * 4096;
    if (isB) *(float4*)&Sall[cbase + (size_t)n * 64 + jc * 4] = cs;
    else if (l > 0) *(float4*)&Mcum[cbase + (size_t)n * 64 + jc * 4] = cs;
    *(float4*)&Srow[cur][rr * LD + jc * 4] = cs;
    float4 bv = make_float4(0.f, 0.f, 0.f, 0.f);
    if (isB) bv = *(const float4*)&Bg[cbase + (size_t)n * 64 + jc * 4];

    const float* Mrow = Mg + cbase + jc * 4;
    float4 acc = make_float4(0.f, 0.f, 0.f, 0.f);
#pragma unroll
    for (int u = 0; u < 16; ++u) {
      float4 sv = *(const float4*)&Srow[cur][rr * LD + u * 4];
      float4 m0 = *(const float4*)&Mrow[(4 * u + 0) * 64];
      float4 m1 = *(const float4*)&Mrow[(4 * u + 1) * 64];
      float4 m2 = *(const float4*)&Mrow[(4 * u + 2) * 64];
      float4 m3 = *(const float4*)&Mrow[(4 * u + 3) * 64];
      acc.x = fmaf(sv.x, m0.x, acc.x); acc.y = fmaf(sv.x, m0.y, acc.y);
      acc.z = fmaf(sv.x, m0.z, acc.z); acc.w = fmaf(sv.x, m0.w, acc.w);
      acc.x = fmaf(sv.y, m1.x, acc.x); acc.y = fmaf(sv.y, m1.y, acc.y);
      acc.z = fmaf(sv.y, m1.z, acc.z); acc.w = fmaf(sv.y, m1.w, acc.w);
      acc.x = fmaf(sv.z, m2.x, acc.x); acc.y = fmaf(sv.z, m2.y, acc.y);
      acc.z = fmaf(sv.z, m2.z, acc.z); acc.w = fmaf(sv.z, m2.w, acc.w);
      acc.x = fmaf(sv.w, m3.x, acc.x); acc.y = fmaf(sv.w, m3.y, acc.y);
      acc.z = fmaf(sv.w, m3.z, acc.z); acc.w = fmaf(sv.w, m3.w, acc.w);
    }
    cs = make_float4(acc.x + bv.x, acc.y + bv.y, acc.z + bv.z, acc.w + bv.w);
  }
  if (isB)
    *(float4*)&BGfin[((size_t)g * BB + b) * 4096 + (size_t)n * 64 + jc * 4] = cs;
  else
    *(float4*)&Mcum[((size_t)(g * GSZ) * BB + b) * 4096 + (size_t)n * 64 + jc * 4] = cs;
}

__global__ __launch_bounds__(64, 1) void p2b_kernel(
    const float* __restrict__ Mcum, const float* __restrict__ BGfin,
    float* __restrict__ Sall) {
  __shared__ __align__(16) float Srow[2][4 * LD];
  const int bid  = blockIdx.x;
  const int b    = bid >> 4;
  const int w    = bid & 15;
  const int lane = threadIdx.x;
  const int rr   = lane >> 4;
  const int jc   = lane & 15;
  const int n    = w * 4 + rr;

  float4 cs = make_float4(0.f, 0.f, 0.f, 0.f);

  for (int g2 = 0; g2 < NGRP - 1; ++g2) {
    const int cur = g2 & 1;
    *(float4*)&Srow[cur][rr * LD + jc * 4] = cs;
    float4 bv = *(const float4*)&BGfin[((size_t)g2 * BB + b) * 4096 +
                                       (size_t)n * 64 + jc * 4];
    const float* Mrow =
        Mcum + ((size_t)(g2 * GSZ) * BB + b) * 4096 + jc * 4;
    float4 acc = make_float4(0.f, 0.f, 0.f, 0.f);
#pragma unroll
    for (int u = 0; u < 16; ++u) {
      float4 sv = *(const float4*)&Srow[cur][rr * LD + u * 4];
      float4 m0 = *(const float4*)&Mrow[(4 * u + 0) * 64];
      float4 m1 = *(const float4*)&Mrow[(4 * u + 1) * 64];
      float4 m2 = *(const float4*)&Mrow[(4 * u + 2) * 64];
      float4 m3 = *(const float4*)&Mrow[(4 * u + 3) * 64];
      acc.x = fmaf(sv.x, m0.x, acc.x); acc.y = fmaf(sv.x, m0.y, acc.y);
      acc.z = fmaf(sv.x, m0.z, acc.z); acc.w = fmaf(sv.x, m0.w, acc.w);
      acc.x = fmaf(sv.y, m1.x, acc.x); acc.y = fmaf(sv.y, m1.y, acc.y);
      acc.z = fmaf(sv.y, m1.z, acc.z); acc.w = fmaf(sv.y, m1.w, acc.w);
      acc.x = fmaf(sv.z, m2.x, acc.x); acc.y = fmaf(sv.z, m2.y, acc.y);
      acc.z = fmaf(sv.z, m2.z, acc.z); acc.w = fmaf(sv.z, m2.w, acc.w);
      acc.x = fmaf(sv.w, m3.x, acc.x); acc.y = fmaf(sv.w, m3.y, acc.y);
      acc.z = fmaf(sv.w, m3.z, acc.z); acc.w = fmaf(sv.w, m3.w, acc.w);
    }
    cs = make_float4(acc.x + bv.x, acc.y + bv.y, acc.z + bv.z, acc.w + bv.w);
    *(float4*)&Sall[((size_t)((g2 + 1) * GSZ) * BB + b) * 4096 +
                    (size_t)n * 64 + jc * 4] = cs;
  }
}

__global__ __launch_bounds__(256) void p2c_kernel(
    const float* __restrict__ Mcum, float* __restrict__ Sall) {
  __shared__ __align__(16) float SgT[64][LD];
  __shared__ __align__(16) float Mc[64][LD];
  const int idx = blockIdx.x;
  const int b   = idx & 7;
  const int q   = idx >> 3;
  const int g   = 1 + q / (GSZ - 1);
  const int l   = 1 + q % (GSZ - 1);
  const int c   = g * GSZ + l;
  const int t   = threadIdx.x;
  const size_t cbase = ((size_t)c * BB + b) * 4096;
  const size_t gbase = ((size_t)(g * GSZ) * BB + b) * 4096;
  {
    const int tau = t & 63, c0 = (t >> 6) << 4;
    const float* sgp = Sall + gbase + (size_t)tau * 64 + c0;
    const float* mcp = Mcum + cbase + (size_t)tau * 64 + c0;
#pragma unroll
    for (int u = 0; u < 4; ++u) {
      float4 sv = *(const float4*)&sgp[4 * u];
      SgT[c0 + 4 * u + 0][tau] = sv.x;
      SgT[c0 + 4 * u + 1][tau] = sv.y;
      SgT[c0 + 4 * u + 2][tau] = sv.z;
      SgT[c0 + 4 * u + 3][tau] = sv.w;
      *(float4*)&Mc[tau][c0 + 4 * u] = *(const float4*)&mcp[4 * u];
    }
  }
  __syncthreads();
  const int i0 = (t >> 4) << 2;
  const int j0 = (t & 15) << 2;
  float acc[4][4];
#pragma unroll
  for (int i = 0; i < 4; ++i)
#pragma unroll
    for (int j = 0; j < 4; ++j) acc[i][j] = 0.f;
  for (int m = 0; m < 64; ++m) {
    float4 tv = *(const float4*)&SgT[m][i0];
    float4 kv = *(const float4*)&Mc[m][j0];
    float ta[4] = {tv.x, tv.y, tv.z, tv.w};
    float ka[4] = {kv.x, kv.y, kv.z, kv.w};
#pragma unroll
    for (int i = 0; i < 4; ++i)
#pragma unroll
      for (int j = 0; j < 4; ++j) acc[i][j] = fmaf(ta[i], ka[j], acc[i][j]);
  }
  float* dst = Sall + cbase;
#pragma unroll
  for (int i = 0; i < 4; ++i) {
    float4 d = *(float4*)&dst[(size_t)(i0 + i) * 64 + j0];
    d.x += acc[i][0]; d.y += acc[i][1];
    d.z += acc[i][2]; d.w += acc[i][3];
    *(float4*)&dst[(size_t)(i0 + i) * 64 + j0] = d;
  }
}

// ---------------------------------------------------------------------------
// Phase 3: Gt = (Q K^T)^T ; W = V - K S0^T ; U = T W ;
//   Y = Q S0^T + tril(G) U ; y = tanh(Y) * sigmoid(Z)  -> ys (f16)
// K normalized on load; Gt gather conflict-free remap; Ks slot reused K->W->U.
// ---------------------------------------------------------------------------
__global__ __launch_bounds__(256) void phase3_kernel(
    const float* __restrict__ kvqz, const float* __restrict__ Tg,
    const float* __restrict__ Sall, _Float16* __restrict__ ys) {
  __shared__ __align__(16) float Ks[64][LD];   // K, then W, then U
  __shared__ __align__(16) float Qs[64][LD];
  __shared__ __align__(16) float S0s[64][LD];
  __shared__ __align__(16) float Gts[64][LD];
  const int cb = blockIdx.x;
  const int c  = cb >> 3, b = cb & 7;
  const int t  = threadIdx.x;
  const size_t base = (size_t)cb * 4096;

  {
    const int tau = t >> 2, m0q = (t & 3) << 4;
    const float* src = kvqz + (size_t)((c * 64 + tau) * BB + b) * 256;
    float4 kv[4];
    float ss = 0.f;
#pragma unroll
    for (int u = 0; u < 4; ++u) {
      kv[u] = *(const float4*)&src[m0q + 4 * u];
      ss += dot4(kv[u], kv[u]);
      *(float4*)&Qs[tau][m0q + 4 * u]  = *(const float4*)&src[128 + m0q + 4 * u];
      *(float4*)&S0s[tau][m0q + 4 * u] = *(const float4*)&Sall[base + (size_t)tau * 64 + m0q + 4 * u];
    }
    ss += __shfl_xor(ss, 1);
    ss += __shfl_xor(ss, 2);
    const float sc = 1.f / (sqrtf(ss) + 1e-6f);
#pragma unroll
    for (int u = 0; u < 4; ++u) {
      kv[u].x *= sc; kv[u].y *= sc; kv[u].z *= sc; kv[u].w *= sc;
      *(float4*)&Ks[tau][m0q + 4 * u] = kv[u];
    }
  }
  __syncthreads();

  const int i0 = (t >> 4) << 2;
  const int j0 = (t & 15) << 2;
  const int jc = t & 15;

  {  // Gt[s][tq] = sum_m K[s][m] Q[tq][m]  (tq = jc+16*jj remap)
    float acc[4][4];
#pragma unroll
    for (int i = 0; i < 4; ++i)
#pragma unroll
      for (int j = 0; j < 4; ++j) acc[i][j] = 0.f;
#pragma unroll 2
    for (int m4 = 0; m4 < 64; m4 += 4) {
      float4 kr[4], qr[4];
#pragma unroll
      for (int i = 0; i < 4; ++i) kr[i] = *(const float4*)&Ks[i0 + i][m4];
#pragma unroll
      for (int j = 0; j < 4; ++j) qr[j] = *(const float4*)&Qs[jc + 16 * j][m4];
#pragma unroll
      for (int i = 0; i < 4; ++i)
#pragma unroll
        for (int j = 0; j < 4; ++j) acc[i][j] += dot4(kr[i], qr[j]);
    }
#pragma unroll
    for (int i = 0; i < 4; ++i)
#pragma unroll
      for (int j = 0; j < 4; ++j) Gts[i0 + i][jc + 16 * j] = acc[i][j];
  }

  {  // W[tau][n] = V[tau][n] - sum_m K[tau][m] S0[n][m]  -> Ks slot
    float acc[4][4];
#pragma unroll
    for (int i = 0; i < 4; ++i) {
      const float* vrow = kvqz + (size_t)((c * 64 + i0 + i) * BB + b) * 256 + 64;
      float4 vv = *(const float4*)&vrow[j0];
      acc[i][0] = vv.x; acc[i][1] = vv.y; acc[i][2] = vv.z; acc[i][3] = vv.w;
    }
#pragma unroll 2
    for (int m4 = 0; m4 < 64; m4 += 4) {
      float4 kr[4], sr[4];
#pragma unroll
      for (int i = 0; i < 4; ++i) kr[i] = *(const float4*)&Ks[i0 + i][m4];
#pragma unroll
      for (int j = 0; j < 4; ++j) sr[j] = *(const float4*)&S0s[j0 + j][m4];
#pragma unroll
      for (int i = 0; i < 4; ++i)
#pragma unroll
        for (int j = 0; j < 4; ++j) acc[i][j] -= dot4(kr[i], sr[j]);
    }
    __syncthreads();   // all reads of Ks (stages 1+2) complete
#pragma unroll
    for (int i = 0; i < 4; ++i)
      *(float4*)&Ks[i0 + i][j0] =
          make_float4(acc[i][0], acc[i][1], acc[i][2], acc[i][3]);
  }
  __syncthreads();

  float4 zv[4];
  {  // U[tq][n] = sum_s Tt[s][tq] W[s][n]  (Tt from global; W in Ks slot)
#pragma unroll
    for (int i = 0; i < 4; ++i) {
      const float* zrow = kvqz + (size_t)((c * 64 + i0 + i) * BB + b) * 256 + 192;
      zv[i] = *(const float4*)&zrow[j0];
    }
    float acc[4][4];
#pragma unroll
    for (int i = 0; i < 4; ++i)
#pragma unroll
      for (int j = 0; j < 4; ++j) acc[i][j] = 0.f;
    const float* Tp = Tg + base + i0;
#pragma unroll 4
    for (int s = 0; s < 64; ++s) {
      float4 tv = *(const float4*)&Tp[(size_t)s * 64];   // broadcast per quad
      float4 wv = *(const float4*)&Ks[s][j0];
      float ta[4] = {tv.x, tv.y, tv.z, tv.w};
      float wa[4] = {wv.x, wv.y, wv.z, wv.w};
#pragma unroll
      for (int i = 0; i < 4; ++i)
#pragma unroll
        for (int j = 0; j < 4; ++j) acc[i][j] = fmaf(ta[i], wa[j], acc[i][j]);
    }
    __syncthreads();   // all reads of W complete before overwrite
#pragma unroll
    for (int i = 0; i < 4; ++i)
      *(float4*)&Ks[i0 + i][j0] =
          make_float4(acc[i][0], acc[i][1], acc[i][2], acc[i][3]);
  }
  __syncthreads();

  {  // Y = Q S0^T + tril(G) U ; out (f16)   (U in Ks slot)
    float acc[4][4];
#pragma unroll
    for (int i = 0; i < 4; ++i)
#pragma unroll
      for (int j = 0; j < 4; ++j) acc[i][j] = 0.f;
#pragma unroll 2
    for (int m4 = 0; m4 < 64; m4 += 4) {
      float4 qr[4], sr[4];
#pragma unroll
      for (int i = 0; i < 4; ++i) qr[i] = *(const float4*)&Qs[i0 + i][m4];
#pragma unroll
      for (int j = 0; j < 4; ++j) sr[j] = *(const float4*)&S0s[j0 + j][m4];
#pragma unroll
      for (int i = 0; i < 4; ++i)
#pragma unroll
        for (int j = 0; j < 4; ++j) acc[i][j] += dot4(qr[i], sr[j]);
    }
#pragma unroll 4
    for (int s = 0; s < 64; ++s) {
      float4 gv = *(const float4*)&Gts[s][i0];
      float4 uv = *(const float4*)&Ks[s][j0];
      float ga[4] = {gv.x, gv.y, gv.z, gv.w};
      float ua[4] = {uv.x, uv.y, uv.z, uv.w};
#pragma unroll
      for (int i = 0; i < 4; ++i) {
        float gi = (s <= i0 + i) ? ga[i] : 0.f;
#pragma unroll
        for (int j = 0; j < 4; ++j) acc[i][j] = fmaf(gi, ua[j], acc[i][j]);
      }
    }
#pragma unroll
    for (int i = 0; i < 4; ++i) {
      float za[4] = {zv[i].x, zv[i].y, zv[i].z, zv[i].w};
      _Float16 oh[4];
#pragma unroll
      for (int j = 0; j < 4; ++j) {
        float e2 = __expf(2.f * acc[i][j]);
        float th = 1.f - 2.f / (e2 + 1.f);
        float sg = 1.f / (1.f + __expf(-za[j]));
        oh[j] = (_Float16)(th * sg);
      }
      half4h o4 = {oh[0], oh[1], oh[2], oh[3]};
      *(half4h*)&ys[(size_t)((c * 64 + i0 + i) * BB + b) * 64 + j0] = o4;
    }
  }
}

// ---------------------------------------------------------------------------
extern "C" void kernel_launch(void* const* d_in, const int* in_sizes, int n_in,
                              void* d_out, int out_size, void* d_ws, size_t ws_size,
                              hipStream_t stream) {
  const float* x    = (const float*)d_in[0];
  const float* Win  = (const float*)d_in[1];
  const float* Wk   = (const float*)d_in[2];
  const float* Wv   = (const float*)d_in[3];
  const float* Wq   = (const float*)d_in[4];
  const float* Wz   = (const float*)d_in[5];
  const float* Wout = (const float*)d_in[6];
  float* out = (float*)d_out;

  char* ws = (char*)d_ws;
  // Liveness-checked layout (fp32 unless noted):
  //   [0,1M):    Wfh (f16, [0,512K); fuse_reduce4 -> kvqz GEMM), then
  //              BGfin (1M; p2a -> p2b); [0,128K) reused for late Woh when ws
  //              is small (cvt AFTER p2b).  Strictly sequential.
  //   [1M,17M):  kvqz (kvqz GEMM -> phase3).
  //   [17M,21M): Mcum (p2a -> p2c; l=0 slots carry MGfin for p2b);
  //              ysh (f16) [17M,19M) (phase3 -> final GEMM, after Mcum dead).
  //   [21M,37M): fuse scratch (Wgh f16 [21M,22M), WinTh f16 [22M,26M),
  //              Pg4 [26M,30M)) -- all dead before cvt_x writes xh; then
  //              xh (f16; [21M,53M) if big ws else 16MB halves); then
  //              Tg/Mg/Bg/Sall (phase1 -> phase3).
  //   [54M,54.125M): early Woh (f16) when ws >= 55M — untouched otherwise.
  const bool bigws = ws_size >= (55ull << 20);
  _Float16* Wfh  = (_Float16*)(ws);
  float* BGfin   = (float*)(ws);              // written by p2a (Wfh dead)
  float* kvqz    = (float*)(ws + (1u  << 20));
  _Float16* ysh  = (_Float16*)(ws + (17u << 20));
  float* Mcum    = (float*)(ws + (17u << 20));
  _Float16* Wgh  = (_Float16*)(ws + (21u << 20));
  _Float16* WinTh= (_Float16*)(ws + (22u << 20));
  float* Pg4     = (float*)(ws + (26u << 20));
  float* Tg      = (float*)(ws + (21u << 20));
  float* Mg      = (float*)(ws + (25u << 20));
  float* Bg      = (float*)(ws + (29u << 20));
  float* Sall    = (float*)(ws + (33u << 20));
  _Float16* xh   = (_Float16*)(ws + (21u << 20));
  _Float16* Woh  = bigws ? (_Float16*)(ws + (54u << 20)) : (_Float16*)(ws);

  // fuse-path prep (merged: Win transpose + Wg pack + early Wout cvt)
  fuse_prep_kernel<<<800, 256, 0, stream>>>(
      Wk, Wv, Wq, Wz, Win, Wout, Wgh, WinTh, bigws ? Woh : nullptr);
  gemm_h16_splitk<<<dim3(DIM_ / 64, 256 / 64, FKS), 256, 0, stream>>>(
      Wgh, WinTh, Pg4, 256, DIM_, DI_, DI_ / FKS);
  fuse_reduce4_kernel<<<(256 * DIM_ / 4) / 256, 256, 0, stream>>>(Pg4, Wfh);

  if (bigws) {
    cvt_f16_kernel<<<2048, 256, 0, stream>>>(x, xh, (long)MR_ * DIM_ / 8);
    gemm_h16<<<dim3(256 / 64, MR_ / 64), 256, 0, stream>>>(xh, Wfh, kvqz, MR_, 256, DIM_);
  } else {
    const long half_rows = MR_ / 2;
    for (int h = 0; h < 2; ++h) {
      const float* xs = x + (size_t)h * half_rows * DIM_;
      float* cs = kvqz + (size_t)h * half_rows * 256;
      cvt_f16_kernel<<<2048, 256, 0, stream>>>(xs, xh, half_rows * DIM_ / 8);
      gemm_h16<<<dim3(256 / 64, (int)(half_rows / 64)), 256, 0, stream>>>(
          xh, Wfh, cs, (int)half_rows, 256, DIM_);
    }
  }

  phase1_kernel<<<NCH * BB, 256, 0, stream>>>(kvqz, Tg, Mg, Bg);
  p2a_kernel<<<NGRP * BB * 32, 64, 0, stream>>>(Mg, Bg, Mcum, Sall, BGfin);
  p2b_kernel<<<16 * BB, 64, 0, stream>>>(Mcum, BGfin, Sall);
  p2c_kernel<<<(NGRP - 1) * (GSZ - 1) * BB, 256, 0, stream>>>(Mcum, Sall);
  if (!bigws) {
    // late Wout cvt: [0,128K) is free (Wfh and BGfin both dead).
    cvt_f16_kernel<<<32, 256, 0, stream>>>(Wout, Woh, (long)(DIM_ * NS_ / 8));
  }
  phase3_kernel<<<NCH * BB, 256, 0, stream>>>(kvqz, Tg, Sall, ysh);
  gemm_h16<<<dim3(DIM_ / 64, MR_ / 64), 256, 0, stream>>>(ysh, Woh, out, MR_, DIM_, NS_);
}